// Round 7
// baseline (487.926 us; speedup 1.0000x reference)
//
#include <hip/hip_runtime.h>
#include <hip/hip_fp8.h>
#include <stdint.h>

#define DEVI __device__ __forceinline__

typedef unsigned short u16;
typedef uint8_t u8;
typedef __attribute__((ext_vector_type(8))) __bf16 bf16x8;   // MFMA bf16 A/B frag
typedef __attribute__((ext_vector_type(4))) float f32x4;     // MFMA C/D frag
typedef __attribute__((ext_vector_type(4))) int i32x4;
typedef __attribute__((ext_vector_type(8))) int i32x8;       // MX fp8 A/B frag (32 bytes)

DEVI float b2f(u16 u) { union { unsigned int i; float f; } v; v.i = ((unsigned int)u) << 16; return v.f; }
DEVI u16 f2b(float f) {
  union { float f; unsigned int i; } v; v.f = f;
  unsigned int r = v.i + 0x7fffu + ((v.i >> 16) & 1u);
  return (u16)(r >> 16);
}
DEVI u8 f2f8(float f) { __hip_fp8_e4m3 t(f); return t.__x; }

DEVI void gld_lds16(const void* g, void* l) {
  __builtin_amdgcn_global_load_lds((const __attribute__((address_space(1))) unsigned int*)g,
                                   (__attribute__((address_space(3))) unsigned int*)l, 16, 0, 0);
}

DEVI i32x8 ld32(const u8* p0, const u8* p1) {
  i32x4 lo = *(const i32x4*)p0;
  i32x4 hi = *(const i32x4*)p1;
  return __builtin_shufflevector(lo, hi, 0, 1, 2, 3, 4, 5, 6, 7);
}

// =======================================================================
// Prep / elementwise kernels
// =======================================================================

// rmsnorm -> fp8 e4m3 (h feeds the fp8 MX qkv GEMM directly)
__global__ __launch_bounds__(256) void k_rmsnorm(const float* __restrict__ x,
                                                 const float* __restrict__ g,
                                                 u8* __restrict__ h) {
  const int row = blockIdx.x;
  const int t = threadIdx.x;
  const float4 v = ((const float4*)(x + (size_t)row * 1024))[t];
  float ss = v.x * v.x + v.y * v.y + v.z * v.z + v.w * v.w;
  for (int off = 32; off > 0; off >>= 1) ss += __shfl_down(ss, off);
  __shared__ float red[4];
  if ((t & 63) == 0) red[t >> 6] = ss;
  __syncthreads();
  const float tot = red[0] + red[1] + red[2] + red[3];
  const float sc = rsqrtf(tot * (1.0f / 1024.0f) + 1e-6f);
  const float4 gv = ((const float4*)g)[t];
  uchar4 o;
  o.x = f2f8(v.x * sc * gv.x); o.y = f2f8(v.y * sc * gv.y);
  o.z = f2f8(v.z * sc * gv.z); o.w = f2f8(v.w * sc * gv.w);
  *(uchar4*)(h + (size_t)row * 1024 + t * 4) = o;
}

// dst[c][r] = (bf16) src[r][c]
__global__ __launch_bounds__(256) void k_transpose_cast(const float* __restrict__ src,
                                                        int rows, int cols,
                                                        u16* __restrict__ dst) {
  __shared__ float tile[32][33];
  const int c0 = blockIdx.x * 32, r0 = blockIdx.y * 32;
  const int tx = threadIdx.x, ty = threadIdx.y;
  for (int i = 0; i < 32; i += 8)
    tile[ty + i][tx] = src[(size_t)(r0 + ty + i) * cols + c0 + tx];
  __syncthreads();
  for (int i = 0; i < 32; i += 8)
    dst[(size_t)(c0 + ty + i) * rows + r0 + tx] = f2b(tile[tx][ty + i]);
}

// dst[c][r] = fp8( src[r][c] * 32 )  — w ~ N(0,0.02) sits below e4m3's min
// normal (2^-6); pre-scale by 2^5 into the sweet range and compensate with
// an MX block-scale of 2^-5 in the GEMM (exact pow2, no added error).
__global__ __launch_bounds__(256) void k_transpose_cast_f8(const float* __restrict__ src,
                                                           int rows, int cols,
                                                           u8* __restrict__ dst) {
  __shared__ float tile[32][33];
  const int c0 = blockIdx.x * 32, r0 = blockIdx.y * 32;
  const int tx = threadIdx.x, ty = threadIdx.y;
  for (int i = 0; i < 32; i += 8)
    tile[ty + i][tx] = src[(size_t)(r0 + ty + i) * cols + c0 + tx];
  __syncthreads();
  for (int i = 0; i < 32; i += 8)
    dst[(size_t)(c0 + ty + i) * rows + r0 + tx] = f2f8(tile[tx][ty + i] * 32.0f);
}

// ternary rope on q and k (one row each per block; shared c/s computation),
// bf16 in -> fp8 e4m3 out.
__global__ __launch_bounds__(256) void k_rope_cast(const u16* __restrict__ q16, const u16* __restrict__ k16,
                                                   u8* __restrict__ q8, u8* __restrict__ k8) {
  const int row = blockIdx.x;
  const int pos = row & 4095;
  const int t = threadIdx.x;
  const int j0 = t * 2;                       // pair indices j0, j0+1 in [0,512)
  float c[2], s[2];
#pragma unroll
  for (int u = 0; u < 2; u++) {
    const float e = (float)(j0 + u) * (1.0f / 512.0f);
    const float invf = exp2f(-13.287712379549449f * e);   // 10000^(-e)
    const float ang = (float)pos * invf;
    c[u] = rintf(cosf(ang));
    s[u] = rintf(sinf(ang));
  }
  const u16* qr = q16 + (size_t)row * 1024;
  const u16* kr = k16 + (size_t)row * 1024;
  u8* qo = q8 + (size_t)row * 1024;
  u8* ko = k8 + (size_t)row * 1024;
  const ushort2 qa = *(const ushort2*)(qr + j0), qb = *(const ushort2*)(qr + j0 + 512);
  const ushort2 ka = *(const ushort2*)(kr + j0), kb = *(const ushort2*)(kr + j0 + 512);
  uchar2 o;
  o.x = f2f8(b2f(qa.x) * c[0] - b2f(qb.x) * s[0]);
  o.y = f2f8(b2f(qa.y) * c[1] - b2f(qb.y) * s[1]);
  *(uchar2*)(qo + j0) = o;
  o.x = f2f8(b2f(qb.x) * c[0] + b2f(qa.x) * s[0]);
  o.y = f2f8(b2f(qb.y) * c[1] + b2f(qa.y) * s[1]);
  *(uchar2*)(qo + j0 + 512) = o;
  o.x = f2f8(b2f(ka.x) * c[0] - b2f(kb.x) * s[0]);
  o.y = f2f8(b2f(ka.y) * c[1] - b2f(kb.y) * s[1]);
  *(uchar2*)(ko + j0) = o;
  o.x = f2f8(b2f(kb.x) * c[0] + b2f(ka.x) * s[0]);
  o.y = f2f8(b2f(kb.y) * c[1] + b2f(ka.y) * s[1]);
  *(uchar2*)(ko + j0 + 512) = o;
}

// =======================================================================
// bf16 MFMA GEMM core — double-buffered LDS, counted vmcnt (T4), 256 thr.
// =======================================================================
DEVI void gemm_tile(const u16* __restrict__ A, int lda,
                    const u16* __restrict__ B, int ldb,
                    int K, int m0, int n0,
                    u16* As, u16* Bs, f32x4 acc[4][4]) {
  const int t = threadIdx.x;
  const int sr = t >> 2;
  const int sc = (t & 3) * 8;
  const u16* Ag0 = A + (size_t)(m0 + sr) * lda + sc;
  const u16* Ag1 = A + (size_t)(m0 + 64 + sr) * lda + sc;
  const u16* Bg0 = B + (size_t)(n0 + sr) * ldb + sc;
  const u16* Bg1 = B + (size_t)(n0 + 64 + sr) * ldb + sc;
  u16* Asw = As + t * 8;
  u16* Bsw = Bs + t * 8;

  const int lane = t & 63, qd = lane >> 4, l16 = lane & 15;
  const int wave = t >> 6;
  const int wm = (wave >> 1) * 64, wn = (wave & 1) * 64;
  const int aoff = (wm + l16) * 32 + qd * 8;
  const int boff = (wn + l16) * 32 + qd * 8;

  auto stage = [&](int sel, int k0) {
    u16* Ad = Asw + sel * 4096;
    u16* Bd = Bsw + sel * 4096;
    gld_lds16(Ag0 + k0, Ad);
    gld_lds16(Ag1 + k0, Ad + 2048);
    gld_lds16(Bg0 + k0, Bd);
    gld_lds16(Bg1 + k0, Bd + 2048);
  };

  stage(0, 0);
  int cur = 0;
  for (int k0 = 0; k0 < K; k0 += 32) {
    if (k0 + 32 < K) {
      stage(cur ^ 1, k0 + 32);
      asm volatile("s_waitcnt vmcnt(4)" ::: "memory");
    } else {
      asm volatile("s_waitcnt vmcnt(0)" ::: "memory");
    }
    __builtin_amdgcn_s_barrier();
    const u16* Ard = As + cur * 4096 + aoff;
    const u16* Brd = Bs + cur * 4096 + boff;
    bf16x8 af[4], bfv[4];
#pragma unroll
    for (int i = 0; i < 4; i++) af[i] = *(const bf16x8*)(Ard + i * 16 * 32);
#pragma unroll
    for (int j = 0; j < 4; j++) bfv[j] = *(const bf16x8*)(Brd + j * 16 * 32);
    __builtin_amdgcn_s_setprio(1);
#pragma unroll
    for (int i = 0; i < 4; i++)
#pragma unroll
      for (int j = 0; j < 4; j++)
        acc[i][j] = __builtin_amdgcn_mfma_f32_16x16x32_bf16(af[i], bfv[j], acc[i][j], 0, 0, 0);
    __builtin_amdgcn_s_setprio(0);
    __builtin_amdgcn_s_barrier();
    cur ^= 1;
  }
}

// =======================================================================
// fp8 MX-scaled MFMA GEMM core, 256x256 tile, BK=128, 512 threads (8 waves
// 2Mx4N, wave-tile 128x64) — 8-PHASE schedule (T3): each K-tile split into
// 4 phases of {ds_read frag-pair (+B in ph0) | issue 4 next-tile gld_lds
// (ph0: A, ph1: B) -> s_barrier -> lgkmcnt(0) -> setprio(1) -> 8 MFMA ->
// setprio(0) -> s_barrier}. vmcnt(0) once per K-tile at ph3, youngest
// outstanding load issued 2 phases (~1100 cyc) earlier.
// Hazards: WAR — next-tile stage issues only after the trailing barrier
// that follows every wave's completed reads of that buffer; RAW — reads of
// buf[cur] only after prev tile's ph3 vmcnt+barrier. Same XOR swizzle and
// accumulation order as before -> bit-identical results.
// =======================================================================
#define MX_MFMA(IDX, AV)                                                     \
  _Pragma("unroll") for (int j = 0; j < 4; j++)                              \
      acc[IDX][j] = __builtin_amdgcn_mfma_scale_f32_16x16x128_f8f6f4(        \
          AV, bfr[j], acc[IDX][j], 0, 0, 0, 0x7f7f7f7f, 0, sB);

#define MX_PHASE(I0, I1, EXTRA)                                              \
  {                                                                          \
    i32x8 a0_ = ld32(Ab + aoff + (I0) * 2048, Ab + (aoff ^ 16) + (I0) * 2048); \
    i32x8 a1_ = ld32(Ab + aoff + (I1) * 2048, Ab + (aoff ^ 16) + (I1) * 2048); \
    EXTRA                                                                    \
    __builtin_amdgcn_s_barrier();                                            \
    asm volatile("s_waitcnt lgkmcnt(0)" ::: "memory");                       \
    __builtin_amdgcn_s_setprio(1);                                           \
    MX_MFMA(I0, a0_)                                                         \
    MX_MFMA(I1, a1_)                                                         \
    __builtin_amdgcn_s_setprio(0);                                           \
    __builtin_amdgcn_s_barrier();                                            \
  }

DEVI void gemm_tile_mx2(const u8* __restrict__ A, int lda,
                        const u8* __restrict__ B, int ldb,
                        int K, int m0, int n0,
                        u8* As, u8* Bs, f32x4 acc[8][4], int sB) {
  const int t = threadIdx.x;                          // 0..511
  const int sr = t >> 3;                              // row 0..63 within group
  const int sc = ((t & 7) ^ (sr & 7)) << 4;           // swizzled global 16B chunk
  const u8* Agb = A + (size_t)(m0 + sr) * lda + sc;   // + l*64*lda + k0
  const u8* Bgb = B + (size_t)(n0 + sr) * ldb + sc;
  u8* Asw = As + t * 16;                              // + l*8192 within a half
  u8* Bsw = Bs + t * 16;

  const int lane = t & 63, qd = lane >> 4, l16 = lane & 15;
  const int wave = t >> 6;                            // 0..7
  const int wm = (wave >> 2) * 128, wn = (wave & 3) * 64;
  const int key = l16 & 7;                            // == frag row & 7
  const int c0 = ((qd << 1) ^ key) << 4;              // pos of chunk 2qd
  const int aoff = (wm + l16) * 128 + c0;
  const int boff = (wn + l16) * 128 + c0;

  // prologue: stage tile 0 into buffer 0, drain, sync
#pragma unroll
  for (int l = 0; l < 4; l++) {
    gld_lds16(Agb + (size_t)l * 64 * lda, Asw + l * 8192);
    gld_lds16(Bgb + (size_t)l * 64 * ldb, Bsw + l * 8192);
  }
  asm volatile("s_waitcnt vmcnt(0)" ::: "memory");
  __builtin_amdgcn_s_barrier();

  int cur = 0;
  for (int k0 = 0; k0 < K; k0 += 128) {
    const u8* Ab = As + cur * 32768;
    const u8* Bb = Bs + cur * 32768;
    u8* Ad = Asw + (cur ^ 1) * 32768;
    u8* Bd = Bsw + (cur ^ 1) * 32768;
    const int kn = k0 + 128;
    const bool more = kn < K;

    i32x8 bfr[4];
#pragma unroll
    for (int j = 0; j < 4; j++)
      bfr[j] = ld32(Bb + boff + j * 2048, Bb + (boff ^ 16) + j * 2048);

    // phase 0: frags A0,A1; stage next A half
    MX_PHASE(0, 1,
      if (more) {
        gld_lds16(Agb + kn, Ad);
        gld_lds16(Agb + kn + (size_t)64 * lda, Ad + 8192);
        gld_lds16(Agb + kn + (size_t)128 * lda, Ad + 16384);
        gld_lds16(Agb + kn + (size_t)192 * lda, Ad + 24576);
      })
    // phase 1: frags A2,A3; stage next B half
    MX_PHASE(2, 3,
      if (more) {
        gld_lds16(Bgb + kn, Bd);
        gld_lds16(Bgb + kn + (size_t)64 * ldb, Bd + 8192);
        gld_lds16(Bgb + kn + (size_t)128 * ldb, Bd + 16384);
        gld_lds16(Bgb + kn + (size_t)192 * ldb, Bd + 24576);
      })
    // phase 2: frags A4,A5
    MX_PHASE(4, 5, )
    // phase 3: frags A6,A7; drain next-tile staging (issued >= 2 phases ago)
    MX_PHASE(6, 7,
      if (more) { asm volatile("s_waitcnt vmcnt(0)" ::: "memory"); })
    cur ^= 1;
  }
}

#define ACC_INIT4()                                              \
  f32x4 acc[4][4];                                               \
  _Pragma("unroll") for (int i = 0; i < 4; i++)                  \
      _Pragma("unroll") for (int j = 0; j < 4; j++)              \
          acc[i][j] = f32x4{0.f, 0.f, 0.f, 0.f};

#define ACC_INIT8()                                              \
  f32x4 acc[8][4];                                               \
  _Pragma("unroll") for (int i = 0; i < 8; i++)                  \
      _Pragma("unroll") for (int j = 0; j < 4; j++)              \
          acc[i][j] = f32x4{0.f, 0.f, 0.f, 0.f};

#define GEMM_EPI_IDX4()                                          \
  const int t = threadIdx.x, lane = t & 63, qd = lane >> 4,      \
            l16 = lane & 15, wave = t >> 6;                      \
  const int wm = (wave >> 1) * 64, wn = (wave & 1) * 64;         \
  (void)t;

#define GEMM_EPI_IDX8()                                          \
  const int t = threadIdx.x, lane = t & 63, qd = lane >> 4,      \
            l16 = lane & 15, wave = t >> 6;                      \
  const int wm = (wave >> 2) * 128, wn = (wave & 3) * 64;        \
  (void)t;

// C/D layout (verified m89/m91, dtype-independent): col = lane&15, row = quad*4 + reg

// qkv GEMM (fp8 MX: h fp8 x (wqkv*32 fp8, B-scale 2^-5) -> q16/k16 bf16;
// V section transposed through LDS and written DIRECTLY as fp8 vt.
__global__ __launch_bounds__(512) void k_gemm_qkv(const u8* __restrict__ A, const u8* __restrict__ Bt,
                                                  const float* __restrict__ bias,
                                                  u16* __restrict__ q16, u16* __restrict__ k16,
                                                  u8* __restrict__ vt) {
  __shared__ alignas(16) u8 SMEM[131072];
  u8* As = SMEM;
  u8* Bs = SMEM + 65536;
  ACC_INIT8();
  const int m0 = blockIdx.y * 256, n0 = blockIdx.x * 256;
  gemm_tile_mx2(A, 1024, Bt, 1024, 1024, m0, n0, As, Bs, acc, 0x7a7a7a7a);
  GEMM_EPI_IDX8();
  const int sec = n0 >> 10;                 // 0=q 1=k 2=v (uniform per block)
  const int nb0 = n0 & 1023;
  if (sec < 2) {
    u16* dst = (sec == 0) ? q16 : k16;
#pragma unroll
    for (int i = 0; i < 8; i++) {
      const int mb = m0 + wm + i * 16 + qd * 4;
#pragma unroll
      for (int j = 0; j < 4; j++) {
        const int col = n0 + wn + j * 16 + l16;
        const float bv = bias[col];
        const int dcol = nb0 + wn + j * 16 + l16;
#pragma unroll
        for (int r = 0; r < 4; r++)
          dst[(size_t)(mb + r) * 1024 + dcol] = f2b(acc[i][j][r] + bv);
      }
    }
  } else {
    // V: transpose 256(s) x 256(d) tile via LDS -> vt[b][d][s] fp8, coalesced.
    // GEMM's final barrier guarantees the staging LDS is dead; reuse it.
    // Stride 272 (odd multiple of 16) keeps 16B alignment + rotates banks.
    u8* T = SMEM;
    const int STR = 272;                    // 256*272 = 69632 <= 131072
#pragma unroll
    for (int i = 0; i < 8; i++) {
      const int mloc = wm + i * 16 + qd * 4;
#pragma unroll
      for (int j = 0; j < 4; j++) {
        const int dloc = wn + j * 16 + l16;
        const float bv = bias[n0 + wn + j * 16 + l16];
#pragma unroll
        for (int r = 0; r < 4; r++)
          T[dloc * STR + mloc + r] = f2f8(acc[i][j][r] + bv);
      }
    }
    __syncthreads();
    const int b = m0 >> 12;                 // batch (4096 rows each)
    const int s0 = m0 & 4095;               // seq offset within batch
    const int row = t >> 1, half = (t & 1) * 128;
    u8* dst = vt + ((size_t)(b * 1024 + nb0 + row)) * 4096 + s0 + half;
    const u8* src = T + row * STR + half;
#pragma unroll
    for (int c = 0; c < 8; c++)
      *(i32x4*)(dst + c * 16) = *(const i32x4*)(src + c * 16);
  }
}

// P = 3^(q k^T / 32) fp8, row sums ls (float, pre-quantization).
// Grid (16,16,4); XCD-aware: each XCD owns 2 n-columns x 16 m-tiles.
__global__ __launch_bounds__(512) void k_gemm_scores(const u8* __restrict__ q, const u8* __restrict__ kk,
                                                     u8* __restrict__ P, float* __restrict__ ls) {
  __shared__ alignas(16) u8 SMEM[131072];
  u8* As = SMEM;
  u8* Bs = SMEM + 65536;
  ACC_INIT8();
  const int b = blockIdx.z;
  const u8* A = q + (size_t)b * 4096 * 1024;
  const u8* Bt = kk + (size_t)b * 4096 * 1024;
  const int bid = blockIdx.y * 16 + blockIdx.x;
  const int xcd = bid & 7, idx = bid >> 3;             // idx 0..31
  const int m0 = (idx & 15) * 256;
  const int n0 = ((xcd << 1) | (idx >> 4)) * 256;
  gemm_tile_mx2(A, 1024, Bt, 1024, 1024, m0, n0, As, Bs, acc, 0x7f7f7f7f);
  GEMM_EPI_IDX8();
  const float C3 = 0.04953007814753613f;  // log2(3) / 32
  const size_t Pb = (size_t)b * 4096 * 4096;
  f32x4 rowp[8];
#pragma unroll
  for (int i = 0; i < 8; i++) rowp[i] = f32x4{0.f, 0.f, 0.f, 0.f};
#pragma unroll
  for (int i = 0; i < 8; i++) {
    const int mb = m0 + wm + i * 16 + qd * 4;
#pragma unroll
    for (int j = 0; j < 4; j++) {
      const int col = n0 + wn + j * 16 + l16;
#pragma unroll
      for (int r = 0; r < 4; r++) {
        const float pv = __builtin_amdgcn_exp2f(acc[i][j][r] * C3);
        P[Pb + (size_t)(mb + r) * 4096 + col] = f2f8(pv);
        rowp[i][r] += pv;
      }
    }
  }
#pragma unroll
  for (int m = 1; m < 16; m <<= 1)
#pragma unroll
    for (int i = 0; i < 8; i++) {
      rowp[i].x += __shfl_xor(rowp[i].x, m);
      rowp[i].y += __shfl_xor(rowp[i].y, m);
      rowp[i].z += __shfl_xor(rowp[i].z, m);
      rowp[i].w += __shfl_xor(rowp[i].w, m);
    }
  if (l16 == 0) {
#pragma unroll
    for (int i = 0; i < 8; i++) {
      const int mb = m0 + wm + i * 16 + qd * 4;
#pragma unroll
      for (int r = 0; r < 4; r++)
        atomicAdd(ls + (size_t)b * 4096 + mb + r, rowp[i][r]);
    }
  }
}

// o = (P @ V) / ls  (fp8 x fp8 -> bf16). Grid (4,16,4) = 256 blocks = 1/CU;
// XCD-aware: each XCD owns one n-tile x 8 m-tiles.
__global__ __launch_bounds__(512) void k_gemm_pv(const u8* __restrict__ P, const u8* __restrict__ vt,
                                                 const float* __restrict__ ls, u16* __restrict__ o) {
  __shared__ alignas(16) u8 SMEM[131072];
  u8* As = SMEM;
  u8* Bs = SMEM + 65536;
  ACC_INIT8();
  const int b = blockIdx.z;
  const u8* A = P + (size_t)b * 4096 * 4096;
  const u8* Bt = vt + (size_t)b * 1024 * 4096;
  const int bid = blockIdx.y * 4 + blockIdx.x;         // 0..63
  const int xcd = bid & 7, idx = bid >> 3;             // idx 0..7
  const int m0 = (((xcd & 1) << 3) | idx) * 256;       // 0..15 m-tiles
  const int n0 = (xcd >> 1) * 256;                     // 0..3 n-tiles
  gemm_tile_mx2(A, 4096, Bt, 4096, 4096, m0, n0, As, Bs, acc, 0x7f7f7f7f);
  GEMM_EPI_IDX8();
#pragma unroll
  for (int i = 0; i < 8; i++) {
    const int mb = m0 + wm + i * 16 + qd * 4;
    f32x4 inv;
#pragma unroll
    for (int r = 0; r < 4; r++) inv[r] = 1.0f / ls[(size_t)b * 4096 + mb + r];
#pragma unroll
    for (int j = 0; j < 4; j++) {
      const int col = n0 + wn + j * 16 + l16;
#pragma unroll
      for (int r = 0; r < 4; r++)
        o[(size_t)(b * 4096 + mb + r) * 1024 + col] = f2b(acc[i][j][r] * inv[r]);
    }
  }
}

// out = o @ WprojT^T + bias + x  (bf16 GEMM, natural mapping, fp32 out)
__global__ __launch_bounds__(256) void k_gemm_proj(const u16* __restrict__ A, const u16* __restrict__ Bt,
                                                   const float* __restrict__ bias, const float* __restrict__ x,
                                                   float* __restrict__ out) {
  __shared__ alignas(16) u16 As[8192], Bs[8192];
  ACC_INIT4();
  const int m0 = blockIdx.y * 128, n0 = blockIdx.x * 128;
  gemm_tile(A, 1024, Bt, 1024, 1024, m0, n0, As, Bs, acc);
  GEMM_EPI_IDX4();
#pragma unroll
  for (int i = 0; i < 4; i++) {
    const int mb = m0 + wm + i * 16 + qd * 4;
#pragma unroll
    for (int j = 0; j < 4; j++) {
      const int col = n0 + wn + j * 16 + l16;
      const float bv = bias[col];
#pragma unroll
      for (int r = 0; r < 4; r++) {
        const size_t idxo = (size_t)(mb + r) * 1024 + col;
        out[idxo] = acc[i][j][r] + bv + x[idxo];
      }
    }
  }
}

// =======================================================================
extern "C" void kernel_launch(void* const* d_in, const int* in_sizes, int n_in,
                              void* d_out, int out_size, void* d_ws, size_t ws_size,
                              hipStream_t stream) {
  const float* x     = (const float*)d_in[0];
  const float* g     = (const float*)d_in[1];
  const float* wqkv  = (const float*)d_in[2];
  const float* bqkv  = (const float*)d_in[3];
  const float* wproj = (const float*)d_in[4];
  const float* bproj = (const float*)d_in[5];
  float* out = (float*)d_out;

  char* wsp = (char*)d_ws;
  size_t off = 0;
  auto take = [&](size_t bytes) -> void* {
    off = (off + 255) & ~(size_t)255;
    void* r = wsp + off;
    off += bytes;
    return r;
  };
  // h region: fp8 rmsnorm out (16 MB live) early; reused as bf16 o (PV out) later.
  char* hreg = (char*)take(16384ull * 1024 * 2);
  u8*  h8   = (u8*)hreg;
  u16* o16  = (u16*)hreg;
  u8*  wqT8 = (u8*)take(3072ull * 1024);         // fp8, pre-scaled x32
  u16* wpT  = (u16*)take(1024ull * 1024 * 2);
  u8*  q8   = (u8*)take(16384ull * 1024);
  u8*  k8   = (u8*)take(16384ull * 1024);
  u8*  vt   = (u8*)take(4ull * 1024 * 4096);
  float* ls = (float*)take(16384ull * 4);
  // scratch region: q16/k16 (bf16, 64 MB) live only until rope; P
  // (fp8, 67 MB for all 4 batches) aliases the same region afterwards.
  char* scratch = (char*)take(3ull * 16384 * 1024 * 2);
  u16* q16 = (u16*)scratch;
  u16* k16 = (u16*)(scratch + 16384ull * 1024 * 2);
  u8*  P   = (u8*)scratch;

  k_transpose_cast_f8<<<dim3(3072 / 32, 1024 / 32), dim3(32, 8), 0, stream>>>(wqkv, 1024, 3072, wqT8);
  k_transpose_cast<<<dim3(1024 / 32, 1024 / 32), dim3(32, 8), 0, stream>>>(wproj, 1024, 1024, wpT);
  k_rmsnorm<<<16384, 256, 0, stream>>>(x, g, h8);
  k_gemm_qkv<<<dim3(12, 64), 512, 0, stream>>>(h8, wqT8, bqkv, q16, k16, vt);
  k_rope_cast<<<16384, 256, 0, stream>>>(q16, k16, q8, k8);
  hipMemsetAsync(ls, 0, 16384 * 4, stream);
  k_gemm_scores<<<dim3(16, 16, 4), 512, 0, stream>>>(q8, k8, P, ls);
  k_gemm_pv<<<dim3(4, 16, 4), 512, 0, stream>>>(P, vt, ls, o16);
  k_gemm_proj<<<dim3(8, 128), 256, 0, stream>>>(o16, wpT, bproj, x, out);
}

// Round 8
// 468.560 us; speedup vs baseline: 1.0413x; 1.0413x over previous
//
#include <hip/hip_runtime.h>
#include <hip/hip_fp8.h>
#include <stdint.h>

#define DEVI __device__ __forceinline__

typedef unsigned short u16;
typedef uint8_t u8;
typedef __attribute__((ext_vector_type(8))) __bf16 bf16x8;   // MFMA bf16 A/B frag
typedef __attribute__((ext_vector_type(4))) float f32x4;     // MFMA C/D frag
typedef __attribute__((ext_vector_type(4))) int i32x4;
typedef __attribute__((ext_vector_type(8))) int i32x8;       // MX fp8 A/B frag (32 bytes)

DEVI float b2f(u16 u) { union { unsigned int i; float f; } v; v.i = ((unsigned int)u) << 16; return v.f; }
DEVI u16 f2b(float f) {
  union { float f; unsigned int i; } v; v.f = f;
  unsigned int r = v.i + 0x7fffu + ((v.i >> 16) & 1u);
  return (u16)(r >> 16);
}
DEVI u8 f2f8(float f) { __hip_fp8_e4m3 t(f); return t.__x; }

DEVI void gld_lds16(const void* g, void* l) {
  __builtin_amdgcn_global_load_lds((const __attribute__((address_space(1))) unsigned int*)g,
                                   (__attribute__((address_space(3))) unsigned int*)l, 16, 0, 0);
}

DEVI i32x8 ld32(const u8* p0, const u8* p1) {
  i32x4 lo = *(const i32x4*)p0;
  i32x4 hi = *(const i32x4*)p1;
  return __builtin_shufflevector(lo, hi, 0, 1, 2, 3, 4, 5, 6, 7);
}

// =======================================================================
// Prep / elementwise kernels
// =======================================================================

// rmsnorm -> fp8 e4m3 (h feeds the fp8 MX qkv GEMM directly)
__global__ __launch_bounds__(256) void k_rmsnorm(const float* __restrict__ x,
                                                 const float* __restrict__ g,
                                                 u8* __restrict__ h) {
  const int row = blockIdx.x;
  const int t = threadIdx.x;
  const float4 v = ((const float4*)(x + (size_t)row * 1024))[t];
  float ss = v.x * v.x + v.y * v.y + v.z * v.z + v.w * v.w;
  for (int off = 32; off > 0; off >>= 1) ss += __shfl_down(ss, off);
  __shared__ float red[4];
  if ((t & 63) == 0) red[t >> 6] = ss;
  __syncthreads();
  const float tot = red[0] + red[1] + red[2] + red[3];
  const float sc = rsqrtf(tot * (1.0f / 1024.0f) + 1e-6f);
  const float4 gv = ((const float4*)g)[t];
  uchar4 o;
  o.x = f2f8(v.x * sc * gv.x); o.y = f2f8(v.y * sc * gv.y);
  o.z = f2f8(v.z * sc * gv.z); o.w = f2f8(v.w * sc * gv.w);
  *(uchar4*)(h + (size_t)row * 1024 + t * 4) = o;
}

// dst[c][r] = (bf16) src[r][c]
__global__ __launch_bounds__(256) void k_transpose_cast(const float* __restrict__ src,
                                                        int rows, int cols,
                                                        u16* __restrict__ dst) {
  __shared__ float tile[32][33];
  const int c0 = blockIdx.x * 32, r0 = blockIdx.y * 32;
  const int tx = threadIdx.x, ty = threadIdx.y;
  for (int i = 0; i < 32; i += 8)
    tile[ty + i][tx] = src[(size_t)(r0 + ty + i) * cols + c0 + tx];
  __syncthreads();
  for (int i = 0; i < 32; i += 8)
    dst[(size_t)(c0 + ty + i) * rows + r0 + tx] = f2b(tile[tx][ty + i]);
}

// dst[c][r] = fp8( src[r][c] * 32 )  — w ~ N(0,0.02) sits below e4m3's min
// normal (2^-6); pre-scale by 2^5 into the sweet range and compensate with
// an MX block-scale of 2^-5 in the GEMM (exact pow2, no added error).
__global__ __launch_bounds__(256) void k_transpose_cast_f8(const float* __restrict__ src,
                                                           int rows, int cols,
                                                           u8* __restrict__ dst) {
  __shared__ float tile[32][33];
  const int c0 = blockIdx.x * 32, r0 = blockIdx.y * 32;
  const int tx = threadIdx.x, ty = threadIdx.y;
  for (int i = 0; i < 32; i += 8)
    tile[ty + i][tx] = src[(size_t)(r0 + ty + i) * cols + c0 + tx];
  __syncthreads();
  for (int i = 0; i < 32; i += 8)
    dst[(size_t)(c0 + ty + i) * rows + r0 + tx] = f2f8(tile[tx][ty + i] * 32.0f);
}

// ternary rope on q and k (one row each per block; shared c/s computation),
// bf16 in -> fp8 e4m3 out.
__global__ __launch_bounds__(256) void k_rope_cast(const u16* __restrict__ q16, const u16* __restrict__ k16,
                                                   u8* __restrict__ q8, u8* __restrict__ k8) {
  const int row = blockIdx.x;
  const int pos = row & 4095;
  const int t = threadIdx.x;
  const int j0 = t * 2;                       // pair indices j0, j0+1 in [0,512)
  float c[2], s[2];
#pragma unroll
  for (int u = 0; u < 2; u++) {
    const float e = (float)(j0 + u) * (1.0f / 512.0f);
    const float invf = exp2f(-13.287712379549449f * e);   // 10000^(-e)
    const float ang = (float)pos * invf;
    c[u] = rintf(cosf(ang));
    s[u] = rintf(sinf(ang));
  }
  const u16* qr = q16 + (size_t)row * 1024;
  const u16* kr = k16 + (size_t)row * 1024;
  u8* qo = q8 + (size_t)row * 1024;
  u8* ko = k8 + (size_t)row * 1024;
  const ushort2 qa = *(const ushort2*)(qr + j0), qb = *(const ushort2*)(qr + j0 + 512);
  const ushort2 ka = *(const ushort2*)(kr + j0), kb = *(const ushort2*)(kr + j0 + 512);
  uchar2 o;
  o.x = f2f8(b2f(qa.x) * c[0] - b2f(qb.x) * s[0]);
  o.y = f2f8(b2f(qa.y) * c[1] - b2f(qb.y) * s[1]);
  *(uchar2*)(qo + j0) = o;
  o.x = f2f8(b2f(qb.x) * c[0] + b2f(qa.x) * s[0]);
  o.y = f2f8(b2f(qb.y) * c[1] + b2f(qa.y) * s[1]);
  *(uchar2*)(qo + j0 + 512) = o;
  o.x = f2f8(b2f(ka.x) * c[0] - b2f(kb.x) * s[0]);
  o.y = f2f8(b2f(ka.y) * c[1] - b2f(kb.y) * s[1]);
  *(uchar2*)(ko + j0) = o;
  o.x = f2f8(b2f(kb.x) * c[0] + b2f(ka.x) * s[0]);
  o.y = f2f8(b2f(kb.y) * c[1] + b2f(ka.y) * s[1]);
  *(uchar2*)(ko + j0 + 512) = o;
}

// =======================================================================
// bf16 MFMA GEMM core — double-buffered LDS, counted vmcnt (T4), 256 thr.
// =======================================================================
DEVI void gemm_tile(const u16* __restrict__ A, int lda,
                    const u16* __restrict__ B, int ldb,
                    int K, int m0, int n0,
                    u16* As, u16* Bs, f32x4 acc[4][4]) {
  const int t = threadIdx.x;
  const int sr = t >> 2;
  const int sc = (t & 3) * 8;
  const u16* Ag0 = A + (size_t)(m0 + sr) * lda + sc;
  const u16* Ag1 = A + (size_t)(m0 + 64 + sr) * lda + sc;
  const u16* Bg0 = B + (size_t)(n0 + sr) * ldb + sc;
  const u16* Bg1 = B + (size_t)(n0 + 64 + sr) * ldb + sc;
  u16* Asw = As + t * 8;
  u16* Bsw = Bs + t * 8;

  const int lane = t & 63, qd = lane >> 4, l16 = lane & 15;
  const int wave = t >> 6;
  const int wm = (wave >> 1) * 64, wn = (wave & 1) * 64;
  const int aoff = (wm + l16) * 32 + qd * 8;
  const int boff = (wn + l16) * 32 + qd * 8;

  auto stage = [&](int sel, int k0) {
    u16* Ad = Asw + sel * 4096;
    u16* Bd = Bsw + sel * 4096;
    gld_lds16(Ag0 + k0, Ad);
    gld_lds16(Ag1 + k0, Ad + 2048);
    gld_lds16(Bg0 + k0, Bd);
    gld_lds16(Bg1 + k0, Bd + 2048);
  };

  stage(0, 0);
  int cur = 0;
  for (int k0 = 0; k0 < K; k0 += 32) {
    if (k0 + 32 < K) {
      stage(cur ^ 1, k0 + 32);
      asm volatile("s_waitcnt vmcnt(4)" ::: "memory");
    } else {
      asm volatile("s_waitcnt vmcnt(0)" ::: "memory");
    }
    __builtin_amdgcn_s_barrier();
    const u16* Ard = As + cur * 4096 + aoff;
    const u16* Brd = Bs + cur * 4096 + boff;
    bf16x8 af[4], bfv[4];
#pragma unroll
    for (int i = 0; i < 4; i++) af[i] = *(const bf16x8*)(Ard + i * 16 * 32);
#pragma unroll
    for (int j = 0; j < 4; j++) bfv[j] = *(const bf16x8*)(Brd + j * 16 * 32);
    __builtin_amdgcn_s_setprio(1);
#pragma unroll
    for (int i = 0; i < 4; i++)
#pragma unroll
      for (int j = 0; j < 4; j++)
        acc[i][j] = __builtin_amdgcn_mfma_f32_16x16x32_bf16(af[i], bfv[j], acc[i][j], 0, 0, 0);
    __builtin_amdgcn_s_setprio(0);
    __builtin_amdgcn_s_barrier();
    cur ^= 1;
  }
}

// =======================================================================
// fp8 MX-scaled MFMA GEMM core, 256x256 tile, BK=128, 512 threads (8 waves
// 2Mx4N, wave-tile 128x64) — 4-phase interleave with COUNTED vmcnt (T3+T4,
// never drain-0 in the main loop):
//   iter t (reads buf[cur]):
//     issue stage_A(t+1 -> buf[cur^1])  [4 loads]
//     s_waitcnt vmcnt(4)   // drains tile t's 8 (issued a full iter ago);
//                          // A(t+1) stays in flight -> queue never empty
//     s_barrier            // collective: all waves' tile-t loads landed
//     read all B-frags; 4 phases of {read A-frag pair | (ph0: issue
//     stage_B(t+1)) -> barrier -> lgkmcnt(0) -> setprio(1) -> 8 MFMA ->
//     setprio(0) -> barrier}
// Hazards: WAR-A — stage_A issue follows prev iter's phase-3 trailing
// barrier (every wave's reads lgkmcnt-complete before it); WAR-B — prev
// B reads ended at prev phase 0; RAW — counted-wait-by-all + entry barrier.
// Same XOR swizzle and accumulation order -> bit-identical results.
// =======================================================================
#define MX_MFMA(IDX, AV)                                                     \
  _Pragma("unroll") for (int j = 0; j < 4; j++)                              \
      acc[IDX][j] = __builtin_amdgcn_mfma_scale_f32_16x16x128_f8f6f4(        \
          AV, bfr[j], acc[IDX][j], 0, 0, 0, 0x7f7f7f7f, 0, sB);

#define MX_PHASE(I0, I1, EXTRA)                                              \
  {                                                                          \
    i32x8 a0_ = ld32(Ab + aoff + (I0) * 2048, Ab + (aoff ^ 16) + (I0) * 2048); \
    i32x8 a1_ = ld32(Ab + aoff + (I1) * 2048, Ab + (aoff ^ 16) + (I1) * 2048); \
    EXTRA                                                                    \
    __builtin_amdgcn_s_barrier();                                            \
    asm volatile("s_waitcnt lgkmcnt(0)" ::: "memory");                       \
    __builtin_amdgcn_s_setprio(1);                                           \
    MX_MFMA(I0, a0_)                                                         \
    MX_MFMA(I1, a1_)                                                         \
    __builtin_amdgcn_s_setprio(0);                                           \
    __builtin_amdgcn_s_barrier();                                            \
  }

DEVI void gemm_tile_mx2(const u8* __restrict__ A, int lda,
                        const u8* __restrict__ B, int ldb,
                        int K, int m0, int n0,
                        u8* As, u8* Bs, f32x4 acc[8][4], int sB) {
  const int t = threadIdx.x;                          // 0..511
  const int sr = t >> 3;                              // row 0..63 within group
  const int sc = ((t & 7) ^ (sr & 7)) << 4;           // swizzled global 16B chunk
  const u8* Agb = A + (size_t)(m0 + sr) * lda + sc;   // + l*64*lda + k0
  const u8* Bgb = B + (size_t)(n0 + sr) * ldb + sc;
  u8* Asw = As + t * 16;                              // + l*8192 within a half
  u8* Bsw = Bs + t * 16;

  const int lane = t & 63, qd = lane >> 4, l16 = lane & 15;
  const int wave = t >> 6;                            // 0..7
  const int wm = (wave >> 2) * 128, wn = (wave & 3) * 64;
  const int key = l16 & 7;                            // == frag row & 7
  const int c0 = ((qd << 1) ^ key) << 4;              // pos of chunk 2qd
  const int aoff = (wm + l16) * 128 + c0;
  const int boff = (wn + l16) * 128 + c0;

  auto stageA = [&](int sel, int k0) {
    u8* Ad = Asw + sel * 32768;
#pragma unroll
    for (int l = 0; l < 4; l++)
      gld_lds16(Agb + k0 + (size_t)l * 64 * lda, Ad + l * 8192);
  };
  auto stageB = [&](int sel, int k0) {
    u8* Bd = Bsw + sel * 32768;
#pragma unroll
    for (int l = 0; l < 4; l++)
      gld_lds16(Bgb + k0 + (size_t)l * 64 * ldb, Bd + l * 8192);
  };

  // prologue: tile 0 -> buffer 0 (8 loads in flight; no drain here)
  stageA(0, 0);
  stageB(0, 0);

  int cur = 0;
  for (int k0 = 0; k0 < K; k0 += 128) {
    const u8* Ab = As + cur * 32768;
    const u8* Bb = Bs + cur * 32768;
    const int kn = k0 + 128;
    const bool more = kn < K;

    // issue next-tile A first, then COUNTED wait for current tile's 8
    if (more) {
      stageA(cur ^ 1, kn);
      asm volatile("s_waitcnt vmcnt(4)" ::: "memory");
    } else {
      asm volatile("s_waitcnt vmcnt(0)" ::: "memory");
    }
    __builtin_amdgcn_s_barrier();       // entry: tile t fully in LDS (all waves)

    i32x8 bfr[4];
#pragma unroll
    for (int j = 0; j < 4; j++)
      bfr[j] = ld32(Bb + boff + j * 2048, Bb + (boff ^ 16) + j * 2048);

    // phase 0: frags A0,A1; issue next-tile B
    MX_PHASE(0, 1, if (more) { stageB(cur ^ 1, kn); })
    // phases 1-3: remaining A-frag pairs
    MX_PHASE(2, 3, )
    MX_PHASE(4, 5, )
    MX_PHASE(6, 7, )
    cur ^= 1;
  }
}

#define ACC_INIT4()                                              \
  f32x4 acc[4][4];                                               \
  _Pragma("unroll") for (int i = 0; i < 4; i++)                  \
      _Pragma("unroll") for (int j = 0; j < 4; j++)              \
          acc[i][j] = f32x4{0.f, 0.f, 0.f, 0.f};

#define ACC_INIT8()                                              \
  f32x4 acc[8][4];                                               \
  _Pragma("unroll") for (int i = 0; i < 8; i++)                  \
      _Pragma("unroll") for (int j = 0; j < 4; j++)              \
          acc[i][j] = f32x4{0.f, 0.f, 0.f, 0.f};

#define GEMM_EPI_IDX4()                                          \
  const int t = threadIdx.x, lane = t & 63, qd = lane >> 4,      \
            l16 = lane & 15, wave = t >> 6;                      \
  const int wm = (wave >> 1) * 64, wn = (wave & 1) * 64;         \
  (void)t;

#define GEMM_EPI_IDX8()                                          \
  const int t = threadIdx.x, lane = t & 63, qd = lane >> 4,      \
            l16 = lane & 15, wave = t >> 6;                      \
  const int wm = (wave >> 2) * 128, wn = (wave & 3) * 64;        \
  (void)t;

// C/D layout (verified m89/m91, dtype-independent): col = lane&15, row = quad*4 + reg

// qkv GEMM (fp8 MX: h fp8 x (wqkv*32 fp8, B-scale 2^-5) -> q16/k16 bf16;
// V section transposed through LDS and written DIRECTLY as fp8 vt.
__global__ __launch_bounds__(512) void k_gemm_qkv(const u8* __restrict__ A, const u8* __restrict__ Bt,
                                                  const float* __restrict__ bias,
                                                  u16* __restrict__ q16, u16* __restrict__ k16,
                                                  u8* __restrict__ vt) {
  __shared__ alignas(16) u8 SMEM[131072];
  u8* As = SMEM;
  u8* Bs = SMEM + 65536;
  ACC_INIT8();
  const int m0 = blockIdx.y * 256, n0 = blockIdx.x * 256;
  gemm_tile_mx2(A, 1024, Bt, 1024, 1024, m0, n0, As, Bs, acc, 0x7a7a7a7a);
  GEMM_EPI_IDX8();
  const int sec = n0 >> 10;                 // 0=q 1=k 2=v (uniform per block)
  const int nb0 = n0 & 1023;
  if (sec < 2) {
    u16* dst = (sec == 0) ? q16 : k16;
#pragma unroll
    for (int i = 0; i < 8; i++) {
      const int mb = m0 + wm + i * 16 + qd * 4;
#pragma unroll
      for (int j = 0; j < 4; j++) {
        const int col = n0 + wn + j * 16 + l16;
        const float bv = bias[col];
        const int dcol = nb0 + wn + j * 16 + l16;
#pragma unroll
        for (int r = 0; r < 4; r++)
          dst[(size_t)(mb + r) * 1024 + dcol] = f2b(acc[i][j][r] + bv);
      }
    }
  } else {
    // V: transpose 256(s) x 256(d) tile via LDS -> vt[b][d][s] fp8, coalesced.
    // GEMM's final barrier guarantees the staging LDS is dead; reuse it.
    // Stride 272 (odd multiple of 16) keeps 16B alignment + rotates banks.
    u8* T = SMEM;
    const int STR = 272;                    // 256*272 = 69632 <= 131072
#pragma unroll
    for (int i = 0; i < 8; i++) {
      const int mloc = wm + i * 16 + qd * 4;
#pragma unroll
      for (int j = 0; j < 4; j++) {
        const int dloc = wn + j * 16 + l16;
        const float bv = bias[n0 + wn + j * 16 + l16];
#pragma unroll
        for (int r = 0; r < 4; r++)
          T[dloc * STR + mloc + r] = f2f8(acc[i][j][r] + bv);
      }
    }
    __syncthreads();
    const int b = m0 >> 12;                 // batch (4096 rows each)
    const int s0 = m0 & 4095;               // seq offset within batch
    const int row = t >> 1, half = (t & 1) * 128;
    u8* dst = vt + ((size_t)(b * 1024 + nb0 + row)) * 4096 + s0 + half;
    const u8* src = T + row * STR + half;
#pragma unroll
    for (int c = 0; c < 8; c++)
      *(i32x4*)(dst + c * 16) = *(const i32x4*)(src + c * 16);
  }
}

// P = 3^(q k^T / 32) fp8, row sums ls (float, pre-quantization).
// Grid (16,16,4); XCD-aware: each XCD owns 2 n-columns x 16 m-tiles.
__global__ __launch_bounds__(512) void k_gemm_scores(const u8* __restrict__ q, const u8* __restrict__ kk,
                                                     u8* __restrict__ P, float* __restrict__ ls) {
  __shared__ alignas(16) u8 SMEM[131072];
  u8* As = SMEM;
  u8* Bs = SMEM + 65536;
  ACC_INIT8();
  const int b = blockIdx.z;
  const u8* A = q + (size_t)b * 4096 * 1024;
  const u8* Bt = kk + (size_t)b * 4096 * 1024;
  const int bid = blockIdx.y * 16 + blockIdx.x;
  const int xcd = bid & 7, idx = bid >> 3;             // idx 0..31
  const int m0 = (idx & 15) * 256;
  const int n0 = ((xcd << 1) | (idx >> 4)) * 256;
  gemm_tile_mx2(A, 1024, Bt, 1024, 1024, m0, n0, As, Bs, acc, 0x7f7f7f7f);
  GEMM_EPI_IDX8();
  const float C3 = 0.04953007814753613f;  // log2(3) / 32
  const size_t Pb = (size_t)b * 4096 * 4096;
  f32x4 rowp[8];
#pragma unroll
  for (int i = 0; i < 8; i++) rowp[i] = f32x4{0.f, 0.f, 0.f, 0.f};
#pragma unroll
  for (int i = 0; i < 8; i++) {
    const int mb = m0 + wm + i * 16 + qd * 4;
#pragma unroll
    for (int j = 0; j < 4; j++) {
      const int col = n0 + wn + j * 16 + l16;
#pragma unroll
      for (int r = 0; r < 4; r++) {
        const float pv = __builtin_amdgcn_exp2f(acc[i][j][r] * C3);
        P[Pb + (size_t)(mb + r) * 4096 + col] = f2f8(pv);
        rowp[i][r] += pv;
      }
    }
  }
#pragma unroll
  for (int m = 1; m < 16; m <<= 1)
#pragma unroll
    for (int i = 0; i < 8; i++) {
      rowp[i].x += __shfl_xor(rowp[i].x, m);
      rowp[i].y += __shfl_xor(rowp[i].y, m);
      rowp[i].z += __shfl_xor(rowp[i].z, m);
      rowp[i].w += __shfl_xor(rowp[i].w, m);
    }
  if (l16 == 0) {
#pragma unroll
    for (int i = 0; i < 8; i++) {
      const int mb = m0 + wm + i * 16 + qd * 4;
#pragma unroll
      for (int r = 0; r < 4; r++)
        atomicAdd(ls + (size_t)b * 4096 + mb + r, rowp[i][r]);
    }
  }
}

// o = (P @ V) / ls  (fp8 x fp8 -> bf16). Grid (4,16,4) = 256 blocks = 1/CU;
// XCD-aware: each XCD owns one n-tile x 8 m-tiles.
__global__ __launch_bounds__(512) void k_gemm_pv(const u8* __restrict__ P, const u8* __restrict__ vt,
                                                 const float* __restrict__ ls, u16* __restrict__ o) {
  __shared__ alignas(16) u8 SMEM[131072];
  u8* As = SMEM;
  u8* Bs = SMEM + 65536;
  ACC_INIT8();
  const int b = blockIdx.z;
  const u8* A = P + (size_t)b * 4096 * 4096;
  const u8* Bt = vt + (size_t)b * 1024 * 4096;
  const int bid = blockIdx.y * 4 + blockIdx.x;         // 0..63
  const int xcd = bid & 7, idx = bid >> 3;             // idx 0..7
  const int m0 = (((xcd & 1) << 3) | idx) * 256;       // 0..15 m-tiles
  const int n0 = (xcd >> 1) * 256;                     // 0..3 n-tiles
  gemm_tile_mx2(A, 4096, Bt, 4096, 4096, m0, n0, As, Bs, acc, 0x7f7f7f7f);
  GEMM_EPI_IDX8();
#pragma unroll
  for (int i = 0; i < 8; i++) {
    const int mb = m0 + wm + i * 16 + qd * 4;
    f32x4 inv;
#pragma unroll
    for (int r = 0; r < 4; r++) inv[r] = 1.0f / ls[(size_t)b * 4096 + mb + r];
#pragma unroll
    for (int j = 0; j < 4; j++) {
      const int col = n0 + wn + j * 16 + l16;
#pragma unroll
      for (int r = 0; r < 4; r++)
        o[(size_t)(b * 4096 + mb + r) * 1024 + col] = f2b(acc[i][j][r] * inv[r]);
    }
  }
}

// out = o @ WprojT^T + bias + x  (bf16 GEMM, natural mapping, fp32 out)
__global__ __launch_bounds__(256) void k_gemm_proj(const u16* __restrict__ A, const u16* __restrict__ Bt,
                                                   const float* __restrict__ bias, const float* __restrict__ x,
                                                   float* __restrict__ out) {
  __shared__ alignas(16) u16 As[8192], Bs[8192];
  ACC_INIT4();
  const int m0 = blockIdx.y * 128, n0 = blockIdx.x * 128;
  gemm_tile(A, 1024, Bt, 1024, 1024, m0, n0, As, Bs, acc);
  GEMM_EPI_IDX4();
#pragma unroll
  for (int i = 0; i < 4; i++) {
    const int mb = m0 + wm + i * 16 + qd * 4;
#pragma unroll
    for (int j = 0; j < 4; j++) {
      const int col = n0 + wn + j * 16 + l16;
      const float bv = bias[col];
#pragma unroll
      for (int r = 0; r < 4; r++) {
        const size_t idxo = (size_t)(mb + r) * 1024 + col;
        out[idxo] = acc[i][j][r] + bv + x[idxo];
      }
    }
  }
}

// =======================================================================
extern "C" void kernel_launch(void* const* d_in, const int* in_sizes, int n_in,
                              void* d_out, int out_size, void* d_ws, size_t ws_size,
                              hipStream_t stream) {
  const float* x     = (const float*)d_in[0];
  const float* g     = (const float*)d_in[1];
  const float* wqkv  = (const float*)d_in[2];
  const float* bqkv  = (const float*)d_in[3];
  const float* wproj = (const float*)d_in[4];
  const float* bproj = (const float*)d_in[5];
  float* out = (float*)d_out;

  char* wsp = (char*)d_ws;
  size_t off = 0;
  auto take = [&](size_t bytes) -> void* {
    off = (off + 255) & ~(size_t)255;
    void* r = wsp + off;
    off += bytes;
    return r;
  };
  // h region: fp8 rmsnorm out (16 MB live) early; reused as bf16 o (PV out) later.
  char* hreg = (char*)take(16384ull * 1024 * 2);
  u8*  h8   = (u8*)hreg;
  u16* o16  = (u16*)hreg;
  u8*  wqT8 = (u8*)take(3072ull * 1024);         // fp8, pre-scaled x32
  u16* wpT  = (u16*)take(1024ull * 1024 * 2);
  u8*  q8   = (u8*)take(16384ull * 1024);
  u8*  k8   = (u8*)take(16384ull * 1024);
  u8*  vt   = (u8*)take(4ull * 1024 * 4096);
  float* ls = (float*)take(16384ull * 4);
  // scratch region: q16/k16 (bf16, 64 MB) live only until rope; P
  // (fp8, 67 MB for all 4 batches) aliases the same region afterwards.
  char* scratch = (char*)take(3ull * 16384 * 1024 * 2);
  u16* q16 = (u16*)scratch;
  u16* k16 = (u16*)(scratch + 16384ull * 1024 * 2);
  u8*  P   = (u8*)scratch;

  k_transpose_cast_f8<<<dim3(3072 / 32, 1024 / 32), dim3(32, 8), 0, stream>>>(wqkv, 1024, 3072, wqT8);
  k_transpose_cast<<<dim3(1024 / 32, 1024 / 32), dim3(32, 8), 0, stream>>>(wproj, 1024, 1024, wpT);
  k_rmsnorm<<<16384, 256, 0, stream>>>(x, g, h8);
  k_gemm_qkv<<<dim3(12, 64), 512, 0, stream>>>(h8, wqT8, bqkv, q16, k16, vt);
  k_rope_cast<<<16384, 256, 0, stream>>>(q16, k16, q8, k8);
  hipMemsetAsync(ls, 0, 16384 * 4, stream);
  k_gemm_scores<<<dim3(16, 16, 4), 512, 0, stream>>>(q8, k8, P, ls);
  k_gemm_pv<<<dim3(4, 16, 4), 512, 0, stream>>>(P, vt, ls, o16);
  k_gemm_proj<<<dim3(8, 128), 256, 0, stream>>>(o16, wpT, bproj, x, out);
}

// Round 9
// 459.036 us; speedup vs baseline: 1.0629x; 1.0207x over previous
//
#include <hip/hip_runtime.h>
#include <hip/hip_fp8.h>
#include <stdint.h>

#define DEVI __device__ __forceinline__

typedef unsigned short u16;
typedef uint8_t u8;
typedef __attribute__((ext_vector_type(8))) __bf16 bf16x8;   // MFMA bf16 A/B frag
typedef __attribute__((ext_vector_type(4))) float f32x4;     // MFMA C/D frag
typedef __attribute__((ext_vector_type(4))) int i32x4;
typedef __attribute__((ext_vector_type(8))) int i32x8;       // MX fp8 A/B frag (32 bytes)

DEVI float b2f(u16 u) { union { unsigned int i; float f; } v; v.i = ((unsigned int)u) << 16; return v.f; }
DEVI u16 f2b(float f) {
  union { float f; unsigned int i; } v; v.f = f;
  unsigned int r = v.i + 0x7fffu + ((v.i >> 16) & 1u);
  return (u16)(r >> 16);
}
DEVI u8 f2f8(float f) { __hip_fp8_e4m3 t(f); return t.__x; }

DEVI void gld_lds16(const void* g, void* l) {
  __builtin_amdgcn_global_load_lds((const __attribute__((address_space(1))) unsigned int*)g,
                                   (__attribute__((address_space(3))) unsigned int*)l, 16, 0, 0);
}

DEVI i32x8 ld32(const u8* p0, const u8* p1) {
  i32x4 lo = *(const i32x4*)p0;
  i32x4 hi = *(const i32x4*)p1;
  return __builtin_shufflevector(lo, hi, 0, 1, 2, 3, 4, 5, 6, 7);
}

// =======================================================================
// Prep / elementwise kernels
// =======================================================================

// rmsnorm -> fp8 e4m3 (h feeds the fp8 MX qkv GEMM directly)
__global__ __launch_bounds__(256) void k_rmsnorm(const float* __restrict__ x,
                                                 const float* __restrict__ g,
                                                 u8* __restrict__ h) {
  const int row = blockIdx.x;
  const int t = threadIdx.x;
  const float4 v = ((const float4*)(x + (size_t)row * 1024))[t];
  float ss = v.x * v.x + v.y * v.y + v.z * v.z + v.w * v.w;
  for (int off = 32; off > 0; off >>= 1) ss += __shfl_down(ss, off);
  __shared__ float red[4];
  if ((t & 63) == 0) red[t >> 6] = ss;
  __syncthreads();
  const float tot = red[0] + red[1] + red[2] + red[3];
  const float sc = rsqrtf(tot * (1.0f / 1024.0f) + 1e-6f);
  const float4 gv = ((const float4*)g)[t];
  uchar4 o;
  o.x = f2f8(v.x * sc * gv.x); o.y = f2f8(v.y * sc * gv.y);
  o.z = f2f8(v.z * sc * gv.z); o.w = f2f8(v.w * sc * gv.w);
  *(uchar4*)(h + (size_t)row * 1024 + t * 4) = o;
}

// dst[c][r] = (bf16) src[r][c]
__global__ __launch_bounds__(256) void k_transpose_cast(const float* __restrict__ src,
                                                        int rows, int cols,
                                                        u16* __restrict__ dst) {
  __shared__ float tile[32][33];
  const int c0 = blockIdx.x * 32, r0 = blockIdx.y * 32;
  const int tx = threadIdx.x, ty = threadIdx.y;
  for (int i = 0; i < 32; i += 8)
    tile[ty + i][tx] = src[(size_t)(r0 + ty + i) * cols + c0 + tx];
  __syncthreads();
  for (int i = 0; i < 32; i += 8)
    dst[(size_t)(c0 + ty + i) * rows + r0 + tx] = f2b(tile[tx][ty + i]);
}

// dst[c][r] = fp8( src[r][c] * 32 )  — w ~ N(0,0.02) sits below e4m3's min
// normal (2^-6); pre-scale by 2^5 into the sweet range and compensate with
// an MX block-scale of 2^-5 in the GEMM (exact pow2, no added error).
__global__ __launch_bounds__(256) void k_transpose_cast_f8(const float* __restrict__ src,
                                                           int rows, int cols,
                                                           u8* __restrict__ dst) {
  __shared__ float tile[32][33];
  const int c0 = blockIdx.x * 32, r0 = blockIdx.y * 32;
  const int tx = threadIdx.x, ty = threadIdx.y;
  for (int i = 0; i < 32; i += 8)
    tile[ty + i][tx] = src[(size_t)(r0 + ty + i) * cols + c0 + tx];
  __syncthreads();
  for (int i = 0; i < 32; i += 8)
    dst[(size_t)(c0 + ty + i) * rows + r0 + tx] = f2f8(tile[tx][ty + i] * 32.0f);
}

// ternary rope on q and k (one row each per block; shared c/s computation),
// bf16 in -> fp8 e4m3 out.
__global__ __launch_bounds__(256) void k_rope_cast(const u16* __restrict__ q16, const u16* __restrict__ k16,
                                                   u8* __restrict__ q8, u8* __restrict__ k8) {
  const int row = blockIdx.x;
  const int pos = row & 4095;
  const int t = threadIdx.x;
  const int j0 = t * 2;                       // pair indices j0, j0+1 in [0,512)
  float c[2], s[2];
#pragma unroll
  for (int u = 0; u < 2; u++) {
    const float e = (float)(j0 + u) * (1.0f / 512.0f);
    const float invf = exp2f(-13.287712379549449f * e);   // 10000^(-e)
    const float ang = (float)pos * invf;
    c[u] = rintf(cosf(ang));
    s[u] = rintf(sinf(ang));
  }
  const u16* qr = q16 + (size_t)row * 1024;
  const u16* kr = k16 + (size_t)row * 1024;
  u8* qo = q8 + (size_t)row * 1024;
  u8* ko = k8 + (size_t)row * 1024;
  const ushort2 qa = *(const ushort2*)(qr + j0), qb = *(const ushort2*)(qr + j0 + 512);
  const ushort2 ka = *(const ushort2*)(kr + j0), kb = *(const ushort2*)(kr + j0 + 512);
  uchar2 o;
  o.x = f2f8(b2f(qa.x) * c[0] - b2f(qb.x) * s[0]);
  o.y = f2f8(b2f(qa.y) * c[1] - b2f(qb.y) * s[1]);
  *(uchar2*)(qo + j0) = o;
  o.x = f2f8(b2f(qb.x) * c[0] + b2f(qa.x) * s[0]);
  o.y = f2f8(b2f(qb.y) * c[1] + b2f(qa.y) * s[1]);
  *(uchar2*)(qo + j0 + 512) = o;
  o.x = f2f8(b2f(ka.x) * c[0] - b2f(kb.x) * s[0]);
  o.y = f2f8(b2f(ka.y) * c[1] - b2f(kb.y) * s[1]);
  *(uchar2*)(ko + j0) = o;
  o.x = f2f8(b2f(kb.x) * c[0] + b2f(ka.x) * s[0]);
  o.y = f2f8(b2f(kb.y) * c[1] + b2f(ka.y) * s[1]);
  *(uchar2*)(ko + j0 + 512) = o;
}

// =======================================================================
// bf16 MFMA GEMM core — double-buffered LDS, counted vmcnt (T4): stage
// tile t+1 before computing tile t; wait vmcnt(4) = tile t's loads done,
// tile t+1's 4 still in flight. Raw s_barrier (no implicit vmcnt(0) drain).
// As/Bs are each 8192 u16 (two 8 KB halves).
// =======================================================================
DEVI void gemm_tile(const u16* __restrict__ A, int lda,
                    const u16* __restrict__ B, int ldb,
                    int K, int m0, int n0,
                    u16* As, u16* Bs, f32x4 acc[4][4]) {
  const int t = threadIdx.x;
  const int sr = t >> 2;
  const int sc = (t & 3) * 8;
  const u16* Ag0 = A + (size_t)(m0 + sr) * lda + sc;
  const u16* Ag1 = A + (size_t)(m0 + 64 + sr) * lda + sc;
  const u16* Bg0 = B + (size_t)(n0 + sr) * ldb + sc;
  const u16* Bg1 = B + (size_t)(n0 + 64 + sr) * ldb + sc;
  u16* Asw = As + t * 8;
  u16* Bsw = Bs + t * 8;

  const int lane = t & 63, qd = lane >> 4, l16 = lane & 15;
  const int wave = t >> 6;
  const int wm = (wave >> 1) * 64, wn = (wave & 1) * 64;
  const int aoff = (wm + l16) * 32 + qd * 8;
  const int boff = (wn + l16) * 32 + qd * 8;

  auto stage = [&](int sel, int k0) {
    u16* Ad = Asw + sel * 4096;
    u16* Bd = Bsw + sel * 4096;
    gld_lds16(Ag0 + k0, Ad);
    gld_lds16(Ag1 + k0, Ad + 2048);
    gld_lds16(Bg0 + k0, Bd);
    gld_lds16(Bg1 + k0, Bd + 2048);
  };

  stage(0, 0);
  int cur = 0;
  for (int k0 = 0; k0 < K; k0 += 32) {
    if (k0 + 32 < K) {
      stage(cur ^ 1, k0 + 32);
      asm volatile("s_waitcnt vmcnt(4)" ::: "memory");
    } else {
      asm volatile("s_waitcnt vmcnt(0)" ::: "memory");
    }
    __builtin_amdgcn_s_barrier();
    const u16* Ard = As + cur * 4096 + aoff;
    const u16* Brd = Bs + cur * 4096 + boff;
    bf16x8 af[4], bfv[4];
#pragma unroll
    for (int i = 0; i < 4; i++) af[i] = *(const bf16x8*)(Ard + i * 16 * 32);
#pragma unroll
    for (int j = 0; j < 4; j++) bfv[j] = *(const bf16x8*)(Brd + j * 16 * 32);
    __builtin_amdgcn_s_setprio(1);
#pragma unroll
    for (int i = 0; i < 4; i++)
#pragma unroll
      for (int j = 0; j < 4; j++)
        acc[i][j] = __builtin_amdgcn_mfma_f32_16x16x32_bf16(af[i], bfv[j], acc[i][j], 0, 0, 0);
    __builtin_amdgcn_s_setprio(0);
    __builtin_amdgcn_s_barrier();
    cur ^= 1;
  }
}

// =======================================================================
// fp8 MX-scaled MFMA GEMM core, BK=128, double-buffered LDS + counted
// vmcnt (best measured structure: scores ~113 us, 2 blocks/CU).
// sB is the packed E8M0 B-block-scale (0x7f..=1.0, 0x7a..=2^-5).
// XOR-swizzled LDS: chunk c of row r at position c ^ (r&7) within the row.
// As/Bs are each 32768 bytes (two 16 KB halves); 64 KB LDS -> 2 blocks/CU.
// =======================================================================
DEVI void gemm_tile_mx(const u8* __restrict__ A, int lda,
                       const u8* __restrict__ B, int ldb,
                       int K, int m0, int n0,
                       u8* As, u8* Bs, f32x4 acc[4][4], int sB) {
  const int t = threadIdx.x;
  const int sr = t >> 3;                              // row 0..31 within 32-row group
  const int sc = ((t & 7) ^ (sr & 7)) << 4;           // swizzled global 16B chunk
  const u8* Agb = A + (size_t)(m0 + sr) * lda + sc;   // + l*32*lda + k0
  const u8* Bgb = B + (size_t)(n0 + sr) * ldb + sc;
  u8* Asw = As + t * 16;                              // + l*4096 within a half
  u8* Bsw = Bs + t * 16;

  const int lane = t & 63, qd = lane >> 4, l16 = lane & 15;
  const int wave = t >> 6;
  const int wm = (wave >> 1) * 64, wn = (wave & 1) * 64;
  const int key = l16 & 7;                            // == frag row & 7
  const int c0 = ((qd << 1) ^ key) << 4;              // pos of chunk 2qd
  const int aoff = (wm + l16) * 128 + c0;
  const int boff = (wn + l16) * 128 + c0;

  auto stage = [&](int sel, int k0) {
    u8* Ad = Asw + sel * 16384;
    u8* Bd = Bsw + sel * 16384;
#pragma unroll
    for (int l = 0; l < 4; l++) {
      gld_lds16(Agb + k0 + (size_t)l * 32 * lda, Ad + l * 4096);
      gld_lds16(Bgb + k0 + (size_t)l * 32 * ldb, Bd + l * 4096);
    }
  };

  stage(0, 0);
  int cur = 0;
  for (int k0 = 0; k0 < K; k0 += 128) {
    if (k0 + 128 < K) {
      stage(cur ^ 1, k0 + 128);
      asm volatile("s_waitcnt vmcnt(8)" ::: "memory");   // tile t done; t+1 in flight
    } else {
      asm volatile("s_waitcnt vmcnt(0)" ::: "memory");
    }
    __builtin_amdgcn_s_barrier();
    const u8* Ab = As + cur * 16384;
    const u8* Bb = Bs + cur * 16384;
    i32x8 a[4], b[4];
#pragma unroll
    for (int i = 0; i < 4; i++)
      a[i] = ld32(Ab + aoff + i * 2048, Ab + (aoff ^ 16) + i * 2048);
#pragma unroll
    for (int j = 0; j < 4; j++)
      b[j] = ld32(Bb + boff + j * 2048, Bb + (boff ^ 16) + j * 2048);
    __builtin_amdgcn_s_setprio(1);
#pragma unroll
    for (int i = 0; i < 4; i++)
#pragma unroll
      for (int j = 0; j < 4; j++)
        acc[i][j] = __builtin_amdgcn_mfma_scale_f32_16x16x128_f8f6f4(
            a[i], b[j], acc[i][j], 0 /*cbsz: fp8*/, 0 /*blgp: fp8*/,
            0, 0x7f7f7f7f, 0, sB);                      // E8M0 scales
    __builtin_amdgcn_s_setprio(0);
    __builtin_amdgcn_s_barrier();
    cur ^= 1;
  }
}

#define ACC_INIT()                                               \
  f32x4 acc[4][4];                                               \
  _Pragma("unroll") for (int i = 0; i < 4; i++)                  \
      _Pragma("unroll") for (int j = 0; j < 4; j++)              \
          acc[i][j] = f32x4{0.f, 0.f, 0.f, 0.f};

#define GEMM_EPI_IDX()                                           \
  const int t = threadIdx.x, lane = t & 63, qd = lane >> 4,      \
            l16 = lane & 15, wave = t >> 6;                      \
  const int wm = (wave >> 1) * 64, wn = (wave & 1) * 64;         \
  (void)t;

// C/D layout (verified m89/m91, dtype-independent): col = lane&15, row = quad*4 + reg

// qkv GEMM (fp8 MX: h fp8 x (wqkv*32 fp8, B-scale 2^-5) -> q16/k16 bf16;
// V section is transposed through LDS and written DIRECTLY as fp8 vt
// (k_vt kernel eliminated).
__global__ __launch_bounds__(256) void k_gemm_qkv(const u8* __restrict__ A, const u8* __restrict__ Bt,
                                                  const float* __restrict__ bias,
                                                  u16* __restrict__ q16, u16* __restrict__ k16,
                                                  u8* __restrict__ vt) {
  __shared__ alignas(16) u8 As[32768], Bs[32768];
  ACC_INIT();
  const int m0 = blockIdx.y * 128, n0 = blockIdx.x * 128;
  gemm_tile_mx(A, 1024, Bt, 1024, 1024, m0, n0, As, Bs, acc, 0x7a7a7a7a);
  GEMM_EPI_IDX();
  const int sec = n0 >> 10;                 // 0=q 1=k 2=v (uniform per block)
  const int nb0 = n0 & 1023;
  if (sec < 2) {
    u16* dst = (sec == 0) ? q16 : k16;
#pragma unroll
    for (int i = 0; i < 4; i++) {
      const int mb = m0 + wm + i * 16 + qd * 4;
#pragma unroll
      for (int j = 0; j < 4; j++) {
        const int col = n0 + wn + j * 16 + l16;
        const float bv = bias[col];
        const int dcol = nb0 + wn + j * 16 + l16;
#pragma unroll
        for (int r = 0; r < 4; r++)
          dst[(size_t)(mb + r) * 1024 + dcol] = f2b(acc[i][j][r] + bv);
      }
    }
  } else {
    // V: transpose 128(m) x 128(d) tile via LDS -> vt[b][d][s] fp8, coalesced.
    // GEMM's final barrier guarantees As is dead; reuse it. stride 144 keeps
    // 16B-aligned rows for vectorized readback.
    u8* T = As;
    const int STR = 144;
#pragma unroll
    for (int i = 0; i < 4; i++) {
      const int mloc = wm + i * 16 + qd * 4;
#pragma unroll
      for (int j = 0; j < 4; j++) {
        const int dloc = wn + j * 16 + l16;
        const float bv = bias[n0 + wn + j * 16 + l16];
#pragma unroll
        for (int r = 0; r < 4; r++)
          T[dloc * STR + mloc + r] = f2f8(acc[i][j][r] + bv);
      }
    }
    __syncthreads();
    const int b = m0 >> 12;                 // batch (4096 rows each)
    const int s0 = m0 & 4095;               // seq offset within batch
    const int row = t >> 1, half = (t & 1) * 64;
    u8* dst = vt + ((size_t)(b * 1024 + nb0 + row)) * 4096 + s0 + half;
#pragma unroll
    for (int c = 0; c < 4; c++)
      *(i32x4*)(dst + c * 16) = *(const i32x4*)(T + row * STR + half + c * 16);
  }
}

// P = 3^(q k^T / 32) fp8, row sums ls (float, pre-quantization). XCD 16m x 8n.
__global__ __launch_bounds__(256) void k_gemm_scores(const u8* __restrict__ q, const u8* __restrict__ kk,
                                                     u8* __restrict__ P, float* __restrict__ ls) {
  __shared__ alignas(16) u8 As[32768], Bs[32768];
  ACC_INIT();
  const int b = blockIdx.z;
  const u8* A = q + (size_t)b * 4096 * 1024;
  const u8* Bt = kk + (size_t)b * 4096 * 1024;
  const int bid = blockIdx.y * 32 + blockIdx.x;
  const int xcd = bid & 7, idx = bid >> 3;
  const int m0 = ((xcd >> 2) * 16 + (idx & 15)) * 128;
  const int n0 = ((xcd & 3) * 8 + (idx >> 4)) * 128;
  gemm_tile_mx(A, 1024, Bt, 1024, 1024, m0, n0, As, Bs, acc, 0x7f7f7f7f);
  GEMM_EPI_IDX();
  const float C3 = 0.04953007814753613f;  // log2(3) / 32
  const size_t Pb = (size_t)b * 4096 * 4096;
  f32x4 rowp[4];
#pragma unroll
  for (int i = 0; i < 4; i++) rowp[i] = f32x4{0.f, 0.f, 0.f, 0.f};
#pragma unroll
  for (int i = 0; i < 4; i++) {
    const int mb = m0 + wm + i * 16 + qd * 4;
#pragma unroll
    for (int j = 0; j < 4; j++) {
      const int col = n0 + wn + j * 16 + l16;
#pragma unroll
      for (int r = 0; r < 4; r++) {
        const float pv = __builtin_amdgcn_exp2f(acc[i][j][r] * C3);
        P[Pb + (size_t)(mb + r) * 4096 + col] = f2f8(pv);
        rowp[i][r] += pv;
      }
    }
  }
#pragma unroll
  for (int m = 1; m < 16; m <<= 1)
#pragma unroll
    for (int i = 0; i < 4; i++) {
      rowp[i].x += __shfl_xor(rowp[i].x, m);
      rowp[i].y += __shfl_xor(rowp[i].y, m);
      rowp[i].z += __shfl_xor(rowp[i].z, m);
      rowp[i].w += __shfl_xor(rowp[i].w, m);
    }
  if (l16 == 0) {
#pragma unroll
    for (int i = 0; i < 4; i++) {
      const int mb = m0 + wm + i * 16 + qd * 4;
#pragma unroll
      for (int r = 0; r < 4; r++)
        atomicAdd(ls + (size_t)b * 4096 + mb + r, rowp[i][r]);
    }
  }
}

// o = (P @ V) / ls  (fp8 x fp8 -> bf16). XCD 8m x 4n.
__global__ __launch_bounds__(256) void k_gemm_pv(const u8* __restrict__ P, const u8* __restrict__ vt,
                                                 const float* __restrict__ ls, u16* __restrict__ o) {
  __shared__ alignas(16) u8 As[32768], Bs[32768];
  ACC_INIT();
  const int b = blockIdx.z;
  const u8* A = P + (size_t)b * 4096 * 4096;
  const u8* Bt = vt + (size_t)b * 1024 * 4096;
  const int bid = blockIdx.y * 8 + blockIdx.x;
  const int xcd = bid & 7, idx = bid >> 3;
  const int m0 = ((xcd >> 1) * 8 + (idx & 7)) * 128;
  const int n0 = ((xcd & 1) * 4 + (idx >> 3)) * 128;
  gemm_tile_mx(A, 4096, Bt, 4096, 4096, m0, n0, As, Bs, acc, 0x7f7f7f7f);
  GEMM_EPI_IDX();
#pragma unroll
  for (int i = 0; i < 4; i++) {
    const int mb = m0 + wm + i * 16 + qd * 4;
    f32x4 inv;
#pragma unroll
    for (int r = 0; r < 4; r++) inv[r] = 1.0f / ls[(size_t)b * 4096 + mb + r];
#pragma unroll
    for (int j = 0; j < 4; j++) {
      const int col = n0 + wn + j * 16 + l16;
#pragma unroll
      for (int r = 0; r < 4; r++)
        o[(size_t)(b * 4096 + mb + r) * 1024 + col] = f2b(acc[i][j][r] * inv[r]);
    }
  }
}

// out = o @ WprojT^T + bias + x  (bf16 GEMM, natural mapping, fp32 out)
__global__ __launch_bounds__(256) void k_gemm_proj(const u16* __restrict__ A, const u16* __restrict__ Bt,
                                                   const float* __restrict__ bias, const float* __restrict__ x,
                                                   float* __restrict__ out) {
  __shared__ alignas(16) u16 As[8192], Bs[8192];
  ACC_INIT();
  const int m0 = blockIdx.y * 128, n0 = blockIdx.x * 128;
  gemm_tile(A, 1024, Bt, 1024, 1024, m0, n0, As, Bs, acc);
  GEMM_EPI_IDX();
#pragma unroll
  for (int i = 0; i < 4; i++) {
    const int mb = m0 + wm + i * 16 + qd * 4;
#pragma unroll
    for (int j = 0; j < 4; j++) {
      const int col = n0 + wn + j * 16 + l16;
      const float bv = bias[col];
#pragma unroll
      for (int r = 0; r < 4; r++) {
        const size_t idxo = (size_t)(mb + r) * 1024 + col;
        out[idxo] = acc[i][j][r] + bv + x[idxo];
      }
    }
  }
}

// =======================================================================
extern "C" void kernel_launch(void* const* d_in, const int* in_sizes, int n_in,
                              void* d_out, int out_size, void* d_ws, size_t ws_size,
                              hipStream_t stream) {
  const float* x     = (const float*)d_in[0];
  const float* g     = (const float*)d_in[1];
  const float* wqkv  = (const float*)d_in[2];
  const float* bqkv  = (const float*)d_in[3];
  const float* wproj = (const float*)d_in[4];
  const float* bproj = (const float*)d_in[5];
  float* out = (float*)d_out;

  char* wsp = (char*)d_ws;
  size_t off = 0;
  auto take = [&](size_t bytes) -> void* {
    off = (off + 255) & ~(size_t)255;
    void* r = wsp + off;
    off += bytes;
    return r;
  };
  // h region: fp8 rmsnorm out (16 MB live) early; reused as bf16 o (PV out) later.
  char* hreg = (char*)take(16384ull * 1024 * 2);
  u8*  h8   = (u8*)hreg;
  u16* o16  = (u16*)hreg;
  u8*  wqT8 = (u8*)take(3072ull * 1024);         // fp8, pre-scaled x32
  u16* wpT  = (u16*)take(1024ull * 1024 * 2);
  u8*  q8   = (u8*)take(16384ull * 1024);
  u8*  k8   = (u8*)take(16384ull * 1024);
  u8*  vt   = (u8*)take(4ull * 1024 * 4096);
  float* ls = (float*)take(16384ull * 4);
  // scratch region: q16/k16 (bf16, 64 MB) live only until rope; P
  // (fp8, 67 MB for all 4 batches) aliases the same region afterwards.
  char* scratch = (char*)take(3ull * 16384 * 1024 * 2);
  u16* q16 = (u16*)scratch;
  u16* k16 = (u16*)(scratch + 16384ull * 1024 * 2);
  u8*  P   = (u8*)scratch;

  k_transpose_cast_f8<<<dim3(3072 / 32, 1024 / 32), dim3(32, 8), 0, stream>>>(wqkv, 1024, 3072, wqT8);
  k_transpose_cast<<<dim3(1024 / 32, 1024 / 32), dim3(32, 8), 0, stream>>>(wproj, 1024, 1024, wpT);
  k_rmsnorm<<<16384, 256, 0, stream>>>(x, g, h8);
  k_gemm_qkv<<<dim3(24, 128), 256, 0, stream>>>(h8, wqT8, bqkv, q16, k16, vt);
  k_rope_cast<<<16384, 256, 0, stream>>>(q16, k16, q8, k8);
  hipMemsetAsync(ls, 0, 16384 * 4, stream);
  k_gemm_scores<<<dim3(32, 32, 4), 256, 0, stream>>>(q8, k8, P, ls);
  k_gemm_pv<<<dim3(8, 32, 4), 256, 0, stream>>>(P, vt, ls, o16);
  k_gemm_proj<<<dim3(8, 128), 256, 0, stream>>>(o16, wpT, bproj, x, out);
}

// Round 10
// 450.605 us; speedup vs baseline: 1.0828x; 1.0187x over previous
//
#include <hip/hip_runtime.h>
#include <hip/hip_fp8.h>
#include <stdint.h>

#define DEVI __device__ __forceinline__

typedef unsigned short u16;
typedef uint8_t u8;
typedef __attribute__((ext_vector_type(8))) __bf16 bf16x8;   // MFMA bf16 A/B frag
typedef __attribute__((ext_vector_type(4))) float f32x4;     // MFMA C/D frag
typedef __attribute__((ext_vector_type(4))) int i32x4;
typedef __attribute__((ext_vector_type(8))) int i32x8;       // MX fp8 A/B frag (32 bytes)

DEVI float b2f(u16 u) { union { unsigned int i; float f; } v; v.i = ((unsigned int)u) << 16; return v.f; }
DEVI u16 f2b(float f) {
  union { float f; unsigned int i; } v; v.f = f;
  unsigned int r = v.i + 0x7fffu + ((v.i >> 16) & 1u);
  return (u16)(r >> 16);
}
DEVI u8 f2f8(float f) { __hip_fp8_e4m3 t(f); return t.__x; }

DEVI void gld_lds16(const void* g, void* l) {
  __builtin_amdgcn_global_load_lds((const __attribute__((address_space(1))) unsigned int*)g,
                                   (__attribute__((address_space(3))) unsigned int*)l, 16, 0, 0);
}

DEVI i32x8 ld32(const u8* p0, const u8* p1) {
  i32x4 lo = *(const i32x4*)p0;
  i32x4 hi = *(const i32x4*)p1;
  return __builtin_shufflevector(lo, hi, 0, 1, 2, 3, 4, 5, 6, 7);
}

// =======================================================================
// Prep / elementwise kernels
// =======================================================================

// rmsnorm -> fp8 e4m3 (h feeds the fp8 MX qkv GEMM directly)
__global__ __launch_bounds__(256) void k_rmsnorm(const float* __restrict__ x,
                                                 const float* __restrict__ g,
                                                 u8* __restrict__ h) {
  const int row = blockIdx.x;
  const int t = threadIdx.x;
  const float4 v = ((const float4*)(x + (size_t)row * 1024))[t];
  float ss = v.x * v.x + v.y * v.y + v.z * v.z + v.w * v.w;
  for (int off = 32; off > 0; off >>= 1) ss += __shfl_down(ss, off);
  __shared__ float red[4];
  if ((t & 63) == 0) red[t >> 6] = ss;
  __syncthreads();
  const float tot = red[0] + red[1] + red[2] + red[3];
  const float sc = rsqrtf(tot * (1.0f / 1024.0f) + 1e-6f);
  const float4 gv = ((const float4*)g)[t];
  uchar4 o;
  o.x = f2f8(v.x * sc * gv.x); o.y = f2f8(v.y * sc * gv.y);
  o.z = f2f8(v.z * sc * gv.z); o.w = f2f8(v.w * sc * gv.w);
  *(uchar4*)(h + (size_t)row * 1024 + t * 4) = o;
}

// dst[c][r] = (bf16) src[r][c]
__global__ __launch_bounds__(256) void k_transpose_cast(const float* __restrict__ src,
                                                        int rows, int cols,
                                                        u16* __restrict__ dst) {
  __shared__ float tile[32][33];
  const int c0 = blockIdx.x * 32, r0 = blockIdx.y * 32;
  const int tx = threadIdx.x, ty = threadIdx.y;
  for (int i = 0; i < 32; i += 8)
    tile[ty + i][tx] = src[(size_t)(r0 + ty + i) * cols + c0 + tx];
  __syncthreads();
  for (int i = 0; i < 32; i += 8)
    dst[(size_t)(c0 + ty + i) * rows + r0 + tx] = f2b(tile[tx][ty + i]);
}

// dst[c][r] = fp8( src[r][c] * 32 )  — w ~ N(0,0.02) sits below e4m3's min
// normal (2^-6); pre-scale by 2^5 into the sweet range and compensate with
// an MX block-scale of 2^-5 in the GEMM (exact pow2, no added error).
__global__ __launch_bounds__(256) void k_transpose_cast_f8(const float* __restrict__ src,
                                                           int rows, int cols,
                                                           u8* __restrict__ dst) {
  __shared__ float tile[32][33];
  const int c0 = blockIdx.x * 32, r0 = blockIdx.y * 32;
  const int tx = threadIdx.x, ty = threadIdx.y;
  for (int i = 0; i < 32; i += 8)
    tile[ty + i][tx] = src[(size_t)(r0 + ty + i) * cols + c0 + tx];
  __syncthreads();
  for (int i = 0; i < 32; i += 8)
    dst[(size_t)(c0 + ty + i) * rows + r0 + tx] = f2f8(tile[tx][ty + i] * 32.0f);
}

// ternary rope on q and k (one row each per block; shared c/s computation),
// bf16 in -> fp8 e4m3 out.
__global__ __launch_bounds__(256) void k_rope_cast(const u16* __restrict__ q16, const u16* __restrict__ k16,
                                                   u8* __restrict__ q8, u8* __restrict__ k8) {
  const int row = blockIdx.x;
  const int pos = row & 4095;
  const int t = threadIdx.x;
  const int j0 = t * 2;                       // pair indices j0, j0+1 in [0,512)
  float c[2], s[2];
#pragma unroll
  for (int u = 0; u < 2; u++) {
    const float e = (float)(j0 + u) * (1.0f / 512.0f);
    const float invf = exp2f(-13.287712379549449f * e);   // 10000^(-e)
    const float ang = (float)pos * invf;
    c[u] = rintf(cosf(ang));
    s[u] = rintf(sinf(ang));
  }
  const u16* qr = q16 + (size_t)row * 1024;
  const u16* kr = k16 + (size_t)row * 1024;
  u8* qo = q8 + (size_t)row * 1024;
  u8* ko = k8 + (size_t)row * 1024;
  const ushort2 qa = *(const ushort2*)(qr + j0), qb = *(const ushort2*)(qr + j0 + 512);
  const ushort2 ka = *(const ushort2*)(kr + j0), kb = *(const ushort2*)(kr + j0 + 512);
  uchar2 o;
  o.x = f2f8(b2f(qa.x) * c[0] - b2f(qb.x) * s[0]);
  o.y = f2f8(b2f(qa.y) * c[1] - b2f(qb.y) * s[1]);
  *(uchar2*)(qo + j0) = o;
  o.x = f2f8(b2f(qb.x) * c[0] + b2f(qa.x) * s[0]);
  o.y = f2f8(b2f(qb.y) * c[1] + b2f(qa.y) * s[1]);
  *(uchar2*)(qo + j0 + 512) = o;
  o.x = f2f8(b2f(ka.x) * c[0] - b2f(kb.x) * s[0]);
  o.y = f2f8(b2f(ka.y) * c[1] - b2f(kb.y) * s[1]);
  *(uchar2*)(ko + j0) = o;
  o.x = f2f8(b2f(kb.x) * c[0] + b2f(ka.x) * s[0]);
  o.y = f2f8(b2f(kb.y) * c[1] + b2f(ka.y) * s[1]);
  *(uchar2*)(ko + j0 + 512) = o;
}

// =======================================================================
// bf16 MFMA GEMM core — double-buffered LDS, counted vmcnt (T4): stage
// tile t+1 before computing tile t; wait vmcnt(4) = tile t's loads done,
// tile t+1's 4 still in flight. Raw s_barrier (no implicit vmcnt(0) drain).
// As/Bs are each 8192 u16 (two 8 KB halves).
// =======================================================================
DEVI void gemm_tile(const u16* __restrict__ A, int lda,
                    const u16* __restrict__ B, int ldb,
                    int K, int m0, int n0,
                    u16* As, u16* Bs, f32x4 acc[4][4]) {
  const int t = threadIdx.x;
  const int sr = t >> 2;
  const int sc = (t & 3) * 8;
  const u16* Ag0 = A + (size_t)(m0 + sr) * lda + sc;
  const u16* Ag1 = A + (size_t)(m0 + 64 + sr) * lda + sc;
  const u16* Bg0 = B + (size_t)(n0 + sr) * ldb + sc;
  const u16* Bg1 = B + (size_t)(n0 + 64 + sr) * ldb + sc;
  u16* Asw = As + t * 8;
  u16* Bsw = Bs + t * 8;

  const int lane = t & 63, qd = lane >> 4, l16 = lane & 15;
  const int wave = t >> 6;
  const int wm = (wave >> 1) * 64, wn = (wave & 1) * 64;
  const int aoff = (wm + l16) * 32 + qd * 8;
  const int boff = (wn + l16) * 32 + qd * 8;

  auto stage = [&](int sel, int k0) {
    u16* Ad = Asw + sel * 4096;
    u16* Bd = Bsw + sel * 4096;
    gld_lds16(Ag0 + k0, Ad);
    gld_lds16(Ag1 + k0, Ad + 2048);
    gld_lds16(Bg0 + k0, Bd);
    gld_lds16(Bg1 + k0, Bd + 2048);
  };

  stage(0, 0);
  int cur = 0;
  for (int k0 = 0; k0 < K; k0 += 32) {
    if (k0 + 32 < K) {
      stage(cur ^ 1, k0 + 32);
      asm volatile("s_waitcnt vmcnt(4)" ::: "memory");
    } else {
      asm volatile("s_waitcnt vmcnt(0)" ::: "memory");
    }
    __builtin_amdgcn_s_barrier();
    const u16* Ard = As + cur * 4096 + aoff;
    const u16* Brd = Bs + cur * 4096 + boff;
    bf16x8 af[4], bfv[4];
#pragma unroll
    for (int i = 0; i < 4; i++) af[i] = *(const bf16x8*)(Ard + i * 16 * 32);
#pragma unroll
    for (int j = 0; j < 4; j++) bfv[j] = *(const bf16x8*)(Brd + j * 16 * 32);
    __builtin_amdgcn_s_setprio(1);
#pragma unroll
    for (int i = 0; i < 4; i++)
#pragma unroll
      for (int j = 0; j < 4; j++)
        acc[i][j] = __builtin_amdgcn_mfma_f32_16x16x32_bf16(af[i], bfv[j], acc[i][j], 0, 0, 0);
    __builtin_amdgcn_s_setprio(0);
    __builtin_amdgcn_s_barrier();
    cur ^= 1;
  }
}

// =======================================================================
// fp8 MX-scaled MFMA GEMM core, BK=128, double-buffered LDS + counted
// vmcnt (best measured structure: scores ~113 us, 2 blocks/CU).
// sB is the packed E8M0 B-block-scale (0x7f..=1.0, 0x7a..=2^-5).
// XOR-swizzled LDS: chunk c of row r at position c ^ (r&7) within the row.
// As/Bs are each 32768 bytes (two 16 KB halves); 64 KB LDS -> 2 blocks/CU.
// =======================================================================
DEVI void gemm_tile_mx(const u8* __restrict__ A, int lda,
                       const u8* __restrict__ B, int ldb,
                       int K, int m0, int n0,
                       u8* As, u8* Bs, f32x4 acc[4][4], int sB) {
  const int t = threadIdx.x;
  const int sr = t >> 3;                              // row 0..31 within 32-row group
  const int sc = ((t & 7) ^ (sr & 7)) << 4;           // swizzled global 16B chunk
  const u8* Agb = A + (size_t)(m0 + sr) * lda + sc;   // + l*32*lda + k0
  const u8* Bgb = B + (size_t)(n0 + sr) * ldb + sc;
  u8* Asw = As + t * 16;                              // + l*4096 within a half
  u8* Bsw = Bs + t * 16;

  const int lane = t & 63, qd = lane >> 4, l16 = lane & 15;
  const int wave = t >> 6;
  const int wm = (wave >> 1) * 64, wn = (wave & 1) * 64;
  const int key = l16 & 7;                            // == frag row & 7
  const int c0 = ((qd << 1) ^ key) << 4;              // pos of chunk 2qd
  const int aoff = (wm + l16) * 128 + c0;
  const int boff = (wn + l16) * 128 + c0;

  auto stage = [&](int sel, int k0) {
    u8* Ad = Asw + sel * 16384;
    u8* Bd = Bsw + sel * 16384;
#pragma unroll
    for (int l = 0; l < 4; l++) {
      gld_lds16(Agb + k0 + (size_t)l * 32 * lda, Ad + l * 4096);
      gld_lds16(Bgb + k0 + (size_t)l * 32 * ldb, Bd + l * 4096);
    }
  };

  stage(0, 0);
  int cur = 0;
  for (int k0 = 0; k0 < K; k0 += 128) {
    if (k0 + 128 < K) {
      stage(cur ^ 1, k0 + 128);
      asm volatile("s_waitcnt vmcnt(8)" ::: "memory");   // tile t done; t+1 in flight
    } else {
      asm volatile("s_waitcnt vmcnt(0)" ::: "memory");
    }
    __builtin_amdgcn_s_barrier();
    const u8* Ab = As + cur * 16384;
    const u8* Bb = Bs + cur * 16384;
    i32x8 a[4], b[4];
#pragma unroll
    for (int i = 0; i < 4; i++)
      a[i] = ld32(Ab + aoff + i * 2048, Ab + (aoff ^ 16) + i * 2048);
#pragma unroll
    for (int j = 0; j < 4; j++)
      b[j] = ld32(Bb + boff + j * 2048, Bb + (boff ^ 16) + j * 2048);
    __builtin_amdgcn_s_setprio(1);
#pragma unroll
    for (int i = 0; i < 4; i++)
#pragma unroll
      for (int j = 0; j < 4; j++)
        acc[i][j] = __builtin_amdgcn_mfma_scale_f32_16x16x128_f8f6f4(
            a[i], b[j], acc[i][j], 0 /*cbsz: fp8*/, 0 /*blgp: fp8*/,
            0, 0x7f7f7f7f, 0, sB);                      // E8M0 scales
    __builtin_amdgcn_s_setprio(0);
    __builtin_amdgcn_s_barrier();
    cur ^= 1;
  }
}

#define ACC_INIT()                                               \
  f32x4 acc[4][4];                                               \
  _Pragma("unroll") for (int i = 0; i < 4; i++)                  \
      _Pragma("unroll") for (int j = 0; j < 4; j++)              \
          acc[i][j] = f32x4{0.f, 0.f, 0.f, 0.f};

#define GEMM_EPI_IDX()                                           \
  const int t = threadIdx.x, lane = t & 63, qd = lane >> 4,      \
            l16 = lane & 15, wave = t >> 6;                      \
  const int wm = (wave >> 1) * 64, wn = (wave & 1) * 64;         \
  (void)t;

// C/D layout (verified m89/m91, dtype-independent): col = lane&15, row = quad*4 + reg

// qkv GEMM (fp8 MX: h fp8 x (wqkv*32 fp8, B-scale 2^-5) -> q16/k16 bf16;
// V section is transposed through LDS and written DIRECTLY as fp8 vt.
// T1 XCD swizzle: 3072 blocks, each XCD owns a contiguous 16-mpanel x 24-n
// chunk (A-chunk 2 MB -> per-XCD L2 reuse of A rows). Bijective (3072%8==0).
__global__ __launch_bounds__(256) void k_gemm_qkv(const u8* __restrict__ A, const u8* __restrict__ Bt,
                                                  const float* __restrict__ bias,
                                                  u16* __restrict__ q16, u16* __restrict__ k16,
                                                  u8* __restrict__ vt) {
  __shared__ alignas(16) u8 As[32768], Bs[32768];
  ACC_INIT();
  const int bid = blockIdx.y * 24 + blockIdx.x;       // 0..3071
  const int xcd = bid & 7, idx = bid >> 3;            // idx 0..383
  const int m0 = (xcd * 16 + idx / 24) * 128;         // m-tile 0..127
  const int n0 = (idx % 24) * 128;                    // n-tile 0..23
  gemm_tile_mx(A, 1024, Bt, 1024, 1024, m0, n0, As, Bs, acc, 0x7a7a7a7a);
  GEMM_EPI_IDX();
  const int sec = n0 >> 10;                 // 0=q 1=k 2=v (uniform per block)
  const int nb0 = n0 & 1023;
  if (sec < 2) {
    u16* dst = (sec == 0) ? q16 : k16;
#pragma unroll
    for (int i = 0; i < 4; i++) {
      const int mb = m0 + wm + i * 16 + qd * 4;
#pragma unroll
      for (int j = 0; j < 4; j++) {
        const int col = n0 + wn + j * 16 + l16;
        const float bv = bias[col];
        const int dcol = nb0 + wn + j * 16 + l16;
#pragma unroll
        for (int r = 0; r < 4; r++)
          dst[(size_t)(mb + r) * 1024 + dcol] = f2b(acc[i][j][r] + bv);
      }
    }
  } else {
    // V: transpose 128(m) x 128(d) tile via LDS -> vt[b][d][s] fp8, coalesced.
    // GEMM's final barrier guarantees As is dead; reuse it. stride 144 keeps
    // 16B-aligned rows for vectorized readback.
    u8* T = As;
    const int STR = 144;
#pragma unroll
    for (int i = 0; i < 4; i++) {
      const int mloc = wm + i * 16 + qd * 4;
#pragma unroll
      for (int j = 0; j < 4; j++) {
        const int dloc = wn + j * 16 + l16;
        const float bv = bias[n0 + wn + j * 16 + l16];
#pragma unroll
        for (int r = 0; r < 4; r++)
          T[dloc * STR + mloc + r] = f2f8(acc[i][j][r] + bv);
      }
    }
    __syncthreads();
    const int b = m0 >> 12;                 // batch (4096 rows each)
    const int s0 = m0 & 4095;               // seq offset within batch
    const int row = t >> 1, half = (t & 1) * 64;
    u8* dst = vt + ((size_t)(b * 1024 + nb0 + row)) * 4096 + s0 + half;
#pragma unroll
    for (int c = 0; c < 4; c++)
      *(i32x4*)(dst + c * 16) = *(const i32x4*)(T + row * STR + half + c * 16);
  }
}

// P = 3^(q k^T / 32) fp8, row sums ls (float, pre-quantization). XCD 16m x 8n.
__global__ __launch_bounds__(256) void k_gemm_scores(const u8* __restrict__ q, const u8* __restrict__ kk,
                                                     u8* __restrict__ P, float* __restrict__ ls) {
  __shared__ alignas(16) u8 As[32768], Bs[32768];
  ACC_INIT();
  const int b = blockIdx.z;
  const u8* A = q + (size_t)b * 4096 * 1024;
  const u8* Bt = kk + (size_t)b * 4096 * 1024;
  const int bid = blockIdx.y * 32 + blockIdx.x;
  const int xcd = bid & 7, idx = bid >> 3;
  const int m0 = ((xcd >> 2) * 16 + (idx & 15)) * 128;
  const int n0 = ((xcd & 3) * 8 + (idx >> 4)) * 128;
  gemm_tile_mx(A, 1024, Bt, 1024, 1024, m0, n0, As, Bs, acc, 0x7f7f7f7f);
  GEMM_EPI_IDX();
  const float C3 = 0.04953007814753613f;  // log2(3) / 32
  const size_t Pb = (size_t)b * 4096 * 4096;
  f32x4 rowp[4];
#pragma unroll
  for (int i = 0; i < 4; i++) rowp[i] = f32x4{0.f, 0.f, 0.f, 0.f};
#pragma unroll
  for (int i = 0; i < 4; i++) {
    const int mb = m0 + wm + i * 16 + qd * 4;
#pragma unroll
    for (int j = 0; j < 4; j++) {
      const int col = n0 + wn + j * 16 + l16;
#pragma unroll
      for (int r = 0; r < 4; r++) {
        const float pv = __builtin_amdgcn_exp2f(acc[i][j][r] * C3);
        P[Pb + (size_t)(mb + r) * 4096 + col] = f2f8(pv);
        rowp[i][r] += pv;
      }
    }
  }
#pragma unroll
  for (int m = 1; m < 16; m <<= 1)
#pragma unroll
    for (int i = 0; i < 4; i++) {
      rowp[i].x += __shfl_xor(rowp[i].x, m);
      rowp[i].y += __shfl_xor(rowp[i].y, m);
      rowp[i].z += __shfl_xor(rowp[i].z, m);
      rowp[i].w += __shfl_xor(rowp[i].w, m);
    }
  if (l16 == 0) {
#pragma unroll
    for (int i = 0; i < 4; i++) {
      const int mb = m0 + wm + i * 16 + qd * 4;
#pragma unroll
      for (int r = 0; r < 4; r++)
        atomicAdd(ls + (size_t)b * 4096 + mb + r, rowp[i][r]);
    }
  }
}

// o = (P @ V) / ls  (fp8 x fp8 -> bf16). XCD 8m x 4n.
__global__ __launch_bounds__(256) void k_gemm_pv(const u8* __restrict__ P, const u8* __restrict__ vt,
                                                 const float* __restrict__ ls, u16* __restrict__ o) {
  __shared__ alignas(16) u8 As[32768], Bs[32768];
  ACC_INIT();
  const int b = blockIdx.z;
  const u8* A = P + (size_t)b * 4096 * 4096;
  const u8* Bt = vt + (size_t)b * 1024 * 4096;
  const int bid = blockIdx.y * 8 + blockIdx.x;
  const int xcd = bid & 7, idx = bid >> 3;
  const int m0 = ((xcd >> 1) * 8 + (idx & 7)) * 128;
  const int n0 = ((xcd & 1) * 4 + (idx >> 3)) * 128;
  gemm_tile_mx(A, 4096, Bt, 4096, 4096, m0, n0, As, Bs, acc, 0x7f7f7f7f);
  GEMM_EPI_IDX();
#pragma unroll
  for (int i = 0; i < 4; i++) {
    const int mb = m0 + wm + i * 16 + qd * 4;
    f32x4 inv;
#pragma unroll
    for (int r = 0; r < 4; r++) inv[r] = 1.0f / ls[(size_t)b * 4096 + mb + r];
#pragma unroll
    for (int j = 0; j < 4; j++) {
      const int col = n0 + wn + j * 16 + l16;
#pragma unroll
      for (int r = 0; r < 4; r++)
        o[(size_t)(b * 4096 + mb + r) * 1024 + col] = f2b(acc[i][j][r] * inv[r]);
    }
  }
}

// out = o @ WprojT^T + bias + x  (bf16 GEMM, natural mapping, fp32 out).
// T1 XCD swizzle: 1024 blocks, each XCD owns a 16-mpanel x 8-n chunk
// (A-chunk 4 MB = per-XCD L2). Bijective (1024%8==0).
__global__ __launch_bounds__(256) void k_gemm_proj(const u16* __restrict__ A, const u16* __restrict__ Bt,
                                                   const float* __restrict__ bias, const float* __restrict__ x,
                                                   float* __restrict__ out) {
  __shared__ alignas(16) u16 As[8192], Bs[8192];
  ACC_INIT();
  const int bid = blockIdx.y * 8 + blockIdx.x;        // 0..1023
  const int xcd = bid & 7, idx = bid >> 3;            // idx 0..127
  const int m0 = (xcd * 16 + idx / 8) * 128;          // m-tile 0..127
  const int n0 = (idx % 8) * 128;                     // n-tile 0..7
  gemm_tile(A, 1024, Bt, 1024, 1024, m0, n0, As, Bs, acc);
  GEMM_EPI_IDX();
#pragma unroll
  for (int i = 0; i < 4; i++) {
    const int mb = m0 + wm + i * 16 + qd * 4;
#pragma unroll
    for (int j = 0; j < 4; j++) {
      const int col = n0 + wn + j * 16 + l16;
      const float bv = bias[col];
#pragma unroll
      for (int r = 0; r < 4; r++) {
        const size_t idxo = (size_t)(mb + r) * 1024 + col;
        out[idxo] = acc[i][j][r] + bv + x[idxo];
      }
    }
  }
}

// =======================================================================
extern "C" void kernel_launch(void* const* d_in, const int* in_sizes, int n_in,
                              void* d_out, int out_size, void* d_ws, size_t ws_size,
                              hipStream_t stream) {
  const float* x     = (const float*)d_in[0];
  const float* g     = (const float*)d_in[1];
  const float* wqkv  = (const float*)d_in[2];
  const float* bqkv  = (const float*)d_in[3];
  const float* wproj = (const float*)d_in[4];
  const float* bproj = (const float*)d_in[5];
  float* out = (float*)d_out;

  char* wsp = (char*)d_ws;
  size_t off = 0;
  auto take = [&](size_t bytes) -> void* {
    off = (off + 255) & ~(size_t)255;
    void* r = wsp + off;
    off += bytes;
    return r;
  };
  // h region: fp8 rmsnorm out (16 MB live) early; reused as bf16 o (PV out) later.
  char* hreg = (char*)take(16384ull * 1024 * 2);
  u8*  h8   = (u8*)hreg;
  u16* o16  = (u16*)hreg;
  u8*  wqT8 = (u8*)take(3072ull * 1024);         // fp8, pre-scaled x32
  u16* wpT  = (u16*)take(1024ull * 1024 * 2);
  u8*  q8   = (u8*)take(16384ull * 1024);
  u8*  k8   = (u8*)take(16384ull * 1024);
  u8*  vt   = (u8*)take(4ull * 1024 * 4096);
  float* ls = (float*)take(16384ull * 4);
  // scratch region: q16/k16 (bf16, 64 MB) live only until rope; P
  // (fp8, 67 MB for all 4 batches) aliases the same region afterwards.
  char* scratch = (char*)take(3ull * 16384 * 1024 * 2);
  u16* q16 = (u16*)scratch;
  u16* k16 = (u16*)(scratch + 16384ull * 1024 * 2);
  u8*  P   = (u8*)scratch;

  k_transpose_cast_f8<<<dim3(3072 / 32, 1024 / 32), dim3(32, 8), 0, stream>>>(wqkv, 1024, 3072, wqT8);
  k_transpose_cast<<<dim3(1024 / 32, 1024 / 32), dim3(32, 8), 0, stream>>>(wproj, 1024, 1024, wpT);
  k_rmsnorm<<<16384, 256, 0, stream>>>(x, g, h8);
  k_gemm_qkv<<<dim3(24, 128), 256, 0, stream>>>(h8, wqT8, bqkv, q16, k16, vt);
  k_rope_cast<<<16384, 256, 0, stream>>>(q16, k16, q8, k8);
  hipMemsetAsync(ls, 0, 16384 * 4, stream);
  k_gemm_scores<<<dim3(32, 32, 4), 256, 0, stream>>>(q8, k8, P, ls);
  k_gemm_pv<<<dim3(8, 32, 4), 256, 0, stream>>>(P, vt, ls, o16);
  k_gemm_proj<<<dim3(8, 128), 256, 0, stream>>>(o16, wpT, bproj, x, out);
}